// Round 1
// baseline (4512.187 us; speedup 1.0000x reference)
//
#include <hip/hip_runtime.h>
#include <math.h>

#define NS 128          // T-1 timesteps
#define B_ 128
#define A_ 5
#define X_ 2
#define Y_ 10
#define Z_ 16
#define H_ 128
#define R_ 128
#define LOG2PI_F 1.8378770664093453f

#define BC 4                  // batch rows per workgroup
#define NCHUNK (B_ / BC)      // 32
#define NWG (A_ * NCHUNK)     // 160
#define NTH 256

struct Params {
    const float* __restrict__ y;
    const float* __restrict__ eps;
    const float* __restrict__ eW1; const float* __restrict__ eb1;
    const float* __restrict__ eW2; const float* __restrict__ eb2;
    const float* __restrict__ emW; const float* __restrict__ emb;
    const float* __restrict__ esW; const float* __restrict__ esb;
    const float* __restrict__ pW1; const float* __restrict__ pb1;
    const float* __restrict__ pW2; const float* __restrict__ pb2;
    const float* __restrict__ pmW; const float* __restrict__ pmb;
    const float* __restrict__ psW; const float* __restrict__ psb;
    const float* __restrict__ dW1; const float* __restrict__ db1;
    const float* __restrict__ dW2; const float* __restrict__ db2;
    const float* __restrict__ dmW; const float* __restrict__ dmb;
    const float* __restrict__ dsW; const float* __restrict__ dsb;
    const float* __restrict__ wih; const float* __restrict__ whh;
    const float* __restrict__ bih; const float* __restrict__ bhh;
    int si_ih, sg_ih, si_hh, sg_hh;   // strides: elem(a,g,i) = base + i*si + g*sg
    float* __restrict__ partials;
};

__device__ __forceinline__ float softplusf_(float x) {
    return fmaxf(x, 0.f) + log1pf(expf(-fabsf(x)));
}
__device__ __forceinline__ float sigmoidf_(float x) {
    return 1.f / (1.f + expf(-x));
}

// acc over a segment: out[o] += sum_k W[k*128+o] * x[k], for two batch rows.
// len must be a multiple of 4; x0/x1 point into LDS rows (16B-aligned).
__device__ __forceinline__ void seg_dot2(float& acc0, float& acc1,
        const float* __restrict__ W, int o,
        const float* x0, const float* x1, int len) {
#pragma unroll 8
    for (int k = 0; k < len; k += 4) {
        float w0 = W[(k+0)*H_ + o];
        float w1 = W[(k+1)*H_ + o];
        float w2 = W[(k+2)*H_ + o];
        float w3 = W[(k+3)*H_ + o];
        float4 xa = *(const float4*)(x0 + k);
        float4 xb = *(const float4*)(x1 + k);
        acc0 = fmaf(w0, xa.x, acc0); acc1 = fmaf(w0, xb.x, acc1);
        acc0 = fmaf(w1, xa.y, acc0); acc1 = fmaf(w1, xb.y, acc1);
        acc0 = fmaf(w2, xa.z, acc0); acc1 = fmaf(w2, xb.z, acc1);
        acc0 = fmaf(w3, xa.w, acc0); acc1 = fmaf(w3, xb.w, acc1);
    }
}

// 128 -> 16 head: out[zd] = sum_j W[j*16+zd] * x[j]
__device__ __forceinline__ float head_dot(const float* __restrict__ W, int zd,
                                          const float* x) {
    float acc = 0.f;
#pragma unroll 8
    for (int j = 0; j < H_; j += 4) {
        float4 xv = *(const float4*)(x + j);
        acc = fmaf(W[(j+0)*Z_ + zd], xv.x, acc);
        acc = fmaf(W[(j+1)*Z_ + zd], xv.y, acc);
        acc = fmaf(W[(j+2)*Z_ + zd], xv.z, acc);
        acc = fmaf(W[(j+3)*Z_ + zd], xv.w, acc);
    }
    return acc;
}

__global__ void __launch_bounds__(NTH) vrnn_kernel(Params p) {
    const int tid = threadIdx.x;
    const int a  = blockIdx.x / NCHUNK;
    const int b0 = (blockIdx.x % NCHUNK) * BC;

    __shared__ float h_lds[BC][R_];
    __shared__ float actA[BC][H_];      // enc l1 / dec l1
    __shared__ float actB[BC][H_];      // enc l2 / dec l2
    __shared__ float actC[BC][H_];      // pri l1
    __shared__ float actD[BC][H_];      // pri l2
    __shared__ float ybuf[BC][16];      // y_t (10 used, padded for alignment)
    __shared__ float xbuf[BC][X_];      // x_t
    __shared__ float zbuf[BC][Z_];      // z_t
    __shared__ float mue[BC][Z_], sde[BC][Z_], mup[BC][Z_], sdp[BC][Z_];
    __shared__ float dmu[BC][X_], dsd[BC][X_];
    __shared__ float red[NTH];

    for (int i = tid; i < BC * R_; i += NTH) (&h_lds[0][0])[i] = 0.f;

    const int o  = tid & 127;
    const int bg = tid >> 7;           // 0 or 1
    const int r0 = bg * 2, r1 = r0 + 1;

    float kl_acc = 0.f, nll_acc = 0.f;

    for (int t = 0; t < NS; ++t) {
        __syncthreads();               // protect ybuf/xbuf/h from prev iter readers
        if (tid < 40) {
            int r = tid / 10, j = tid - r * 10;
            ybuf[r][j] = p.y[(size_t)t * (B_ * Y_) + (size_t)(b0 + r) * Y_ + j];
        } else if (tid < 48) {
            int k = tid - 40; int r = k >> 1, xd = k & 1;
            xbuf[r][xd] = p.y[(size_t)(t + 1) * (B_ * Y_) + (size_t)(b0 + r) * Y_ + a * X_ + xd];
        }
        __syncthreads();

        // ---------------- enc layer 1 (in: x2 | y10 | h128) ----------------
        {
            const float* W = p.eW1 + (size_t)a * 140 * H_;
            float acc0 = p.eb1[a * H_ + o], acc1 = acc0;
            float w0 = W[0 * H_ + o], w1 = W[1 * H_ + o];
            acc0 = fmaf(w0, xbuf[r0][0], acc0); acc0 = fmaf(w1, xbuf[r0][1], acc0);
            acc1 = fmaf(w0, xbuf[r1][0], acc1); acc1 = fmaf(w1, xbuf[r1][1], acc1);
            seg_dot2(acc0, acc1, W + 2 * H_, o, &ybuf[r0][0], &ybuf[r1][0], 8);
            float w8 = W[10 * H_ + o], w9 = W[11 * H_ + o];
            acc0 = fmaf(w8, ybuf[r0][8], acc0); acc0 = fmaf(w9, ybuf[r0][9], acc0);
            acc1 = fmaf(w8, ybuf[r1][8], acc1); acc1 = fmaf(w9, ybuf[r1][9], acc1);
            seg_dot2(acc0, acc1, W + 12 * H_, o, &h_lds[r0][0], &h_lds[r1][0], 128);
            actA[r0][o] = fmaxf(acc0, 0.f);
            actA[r1][o] = fmaxf(acc1, 0.f);
        }
        // ---------------- pri layer 1 (in: y10 | h128) ----------------
        {
            const float* W = p.pW1 + (size_t)a * 138 * H_;
            float acc0 = p.pb1[a * H_ + o], acc1 = acc0;
            seg_dot2(acc0, acc1, W, o, &ybuf[r0][0], &ybuf[r1][0], 8);
            float w8 = W[8 * H_ + o], w9 = W[9 * H_ + o];
            acc0 = fmaf(w8, ybuf[r0][8], acc0); acc0 = fmaf(w9, ybuf[r0][9], acc0);
            acc1 = fmaf(w8, ybuf[r1][8], acc1); acc1 = fmaf(w9, ybuf[r1][9], acc1);
            seg_dot2(acc0, acc1, W + 10 * H_, o, &h_lds[r0][0], &h_lds[r1][0], 128);
            actC[r0][o] = fmaxf(acc0, 0.f);
            actC[r1][o] = fmaxf(acc1, 0.f);
        }
        __syncthreads();
        // ---------------- layer 2 (enc & pri) ----------------
        {
            const float* W = p.eW2 + (size_t)a * H_ * H_;
            float acc0 = p.eb2[a * H_ + o], acc1 = acc0;
            seg_dot2(acc0, acc1, W, o, &actA[r0][0], &actA[r1][0], 128);
            actB[r0][o] = fmaxf(acc0, 0.f); actB[r1][o] = fmaxf(acc1, 0.f);
        }
        {
            const float* W = p.pW2 + (size_t)a * H_ * H_;
            float acc0 = p.pb2[a * H_ + o], acc1 = acc0;
            seg_dot2(acc0, acc1, W, o, &actC[r0][0], &actC[r1][0], 128);
            actD[r0][o] = fmaxf(acc0, 0.f); actD[r1][o] = fmaxf(acc1, 0.f);
        }
        __syncthreads();
        // ---------------- 4 gaussian heads (16-wide) ----------------
        {
            int head = tid >> 6;
            int idx = tid & 63; int r = idx >> 4; int zd = idx & 15;
            const float* W; const float* bias; const float* xin;
            if (head == 0)      { W = p.emW; bias = p.emb; xin = &actB[r][0]; }
            else if (head == 1) { W = p.esW; bias = p.esb; xin = &actB[r][0]; }
            else if (head == 2) { W = p.pmW; bias = p.pmb; xin = &actD[r][0]; }
            else                { W = p.psW; bias = p.psb; xin = &actD[r][0]; }
            float v = bias[a * Z_ + zd] + head_dot(W + (size_t)a * H_ * Z_, zd, xin);
            if (head == 0)      mue[r][zd] = v;
            else if (head == 1) sde[r][zd] = softplusf_(v);
            else if (head == 2) mup[r][zd] = v;
            else                sdp[r][zd] = softplusf_(v);
        }
        __syncthreads();
        // ---------------- z sample + KL ----------------
        if (tid < 64) {
            int r = tid >> 4, zd = tid & 15;
            float em = mue[r][zd], es = sde[r][zd], pm = mup[r][zd], ps = sdp[r][zd];
            float e = p.eps[(((size_t)t * A_ + a) * B_ + (b0 + r)) * Z_ + zd];
            float zv = fmaf(e, es, em);
            zbuf[r][zd] = zv;
            float dm = em - pm;
            kl_acc += 0.5f * (2.f * (logf(ps) - logf(es)) + (es * es + dm * dm) / (ps * ps) - 1.f);
        }
        __syncthreads();
        // ---------------- dec layer 1 (in: y10 | z16 | h128) ----------------
        {
            const float* W = p.dW1 + (size_t)a * 154 * H_;
            float acc0 = p.db1[a * H_ + o], acc1 = acc0;
            seg_dot2(acc0, acc1, W, o, &ybuf[r0][0], &ybuf[r1][0], 8);
            float w8 = W[8 * H_ + o], w9 = W[9 * H_ + o];
            acc0 = fmaf(w8, ybuf[r0][8], acc0); acc0 = fmaf(w9, ybuf[r0][9], acc0);
            acc1 = fmaf(w8, ybuf[r1][8], acc1); acc1 = fmaf(w9, ybuf[r1][9], acc1);
            seg_dot2(acc0, acc1, W + 10 * H_, o, &zbuf[r0][0], &zbuf[r1][0], 16);
            seg_dot2(acc0, acc1, W + 26 * H_, o, &h_lds[r0][0], &h_lds[r1][0], 128);
            actA[r0][o] = fmaxf(acc0, 0.f); actA[r1][o] = fmaxf(acc1, 0.f);
        }
        __syncthreads();
        // ---------------- dec layer 2 ----------------
        {
            const float* W = p.dW2 + (size_t)a * H_ * H_;
            float acc0 = p.db2[a * H_ + o], acc1 = acc0;
            seg_dot2(acc0, acc1, W, o, &actA[r0][0], &actA[r1][0], 128);
            actB[r0][o] = fmaxf(acc0, 0.f); actB[r1][o] = fmaxf(acc1, 0.f);
        }
        __syncthreads();
        // ---------------- GRU (uses x, z, old h) ----------------
        float hn0, hn1;
        {
            const float* Wih = p.wih + (size_t)a * 384 * 18;
            const float* Whh = p.whh + (size_t)a * 384 * 128;
            const int g0 = o, g1 = o + 128, g2 = o + 256;
            float A0 = p.bih[a * 384 + g0], A1 = p.bih[a * 384 + g1], A2 = p.bih[a * 384 + g2];
            float B0 = A0, B1 = A1, B2 = A2;
#pragma unroll
            for (int i = 0; i < 2; ++i) {
                float w0 = Wih[i * p.si_ih + g0 * p.sg_ih];
                float w1 = Wih[i * p.si_ih + g1 * p.sg_ih];
                float w2 = Wih[i * p.si_ih + g2 * p.sg_ih];
                float xa = xbuf[r0][i], xb = xbuf[r1][i];
                A0 = fmaf(w0, xa, A0); A1 = fmaf(w1, xa, A1); A2 = fmaf(w2, xa, A2);
                B0 = fmaf(w0, xb, B0); B1 = fmaf(w1, xb, B1); B2 = fmaf(w2, xb, B2);
            }
#pragma unroll 4
            for (int i = 0; i < 16; ++i) {
                int ii = i + 2;
                float w0 = Wih[ii * p.si_ih + g0 * p.sg_ih];
                float w1 = Wih[ii * p.si_ih + g1 * p.sg_ih];
                float w2 = Wih[ii * p.si_ih + g2 * p.sg_ih];
                float xa = zbuf[r0][i], xb = zbuf[r1][i];
                A0 = fmaf(w0, xa, A0); A1 = fmaf(w1, xa, A1); A2 = fmaf(w2, xa, A2);
                B0 = fmaf(w0, xb, B0); B1 = fmaf(w1, xb, B1); B2 = fmaf(w2, xb, B2);
            }
            float C0 = p.bhh[a * 384 + g0], C1 = p.bhh[a * 384 + g1], C2 = p.bhh[a * 384 + g2];
            float D0 = C0, D1 = C1, D2 = C2;
#pragma unroll 4
            for (int i = 0; i < 128; ++i) {
                float w0 = Whh[i * p.si_hh + g0 * p.sg_hh];
                float w1 = Whh[i * p.si_hh + g1 * p.sg_hh];
                float w2 = Whh[i * p.si_hh + g2 * p.sg_hh];
                float xa = h_lds[r0][i], xb = h_lds[r1][i];
                C0 = fmaf(w0, xa, C0); C1 = fmaf(w1, xa, C1); C2 = fmaf(w2, xa, C2);
                D0 = fmaf(w0, xb, D0); D1 = fmaf(w1, xb, D1); D2 = fmaf(w2, xb, D2);
            }
            float rA = sigmoidf_(A0 + C0);
            float zA = sigmoidf_(A1 + C1);
            float nA = tanhf(fmaf(rA, C2, A2));
            float rB = sigmoidf_(B0 + D0);
            float zB = sigmoidf_(B1 + D1);
            float nB = tanhf(fmaf(rB, D2, B2));
            hn0 = fmaf(zA, h_lds[r0][o] - nA, nA);    // (1-z)*n + z*h
            hn1 = fmaf(zB, h_lds[r1][o] - nB, nB);
        }
        // ---------------- dec heads (2-wide), 16 lanes per output ----------------
        {
            int out_id = tid >> 4, part = tid & 15;
            int head = out_id >> 3, sub = out_id & 7, rr = sub >> 1, xd = sub & 1;
            const float* W = (head ? p.dsW : p.dmW) + (size_t)a * H_ * X_;
            float s = 0.f;
            int ib = part * 8;
#pragma unroll
            for (int j = 0; j < 8; ++j)
                s = fmaf(W[(ib + j) * X_ + xd], actB[rr][ib + j], s);
            s += __shfl_xor(s, 1);
            s += __shfl_xor(s, 2);
            s += __shfl_xor(s, 4);
            s += __shfl_xor(s, 8);
            if (part == 0) {
                float v = (head ? p.dsb : p.dmb)[a * X_ + xd] + s;
                if (head) dsd[rr][xd] = softplusf_(v);
                else      dmu[rr][xd] = v;
            }
        }
        __syncthreads();
        h_lds[r0][o] = hn0;
        h_lds[r1][o] = hn1;
        if (tid < 8) {
            int r = tid >> 1, xd = tid & 1;
            float xv = xbuf[r][xd], mu = dmu[r][xd], sd = dsd[r][xd];
            float d = xv - mu;
            nll_acc += 0.5f * (d * d / (sd * sd) + 2.f * logf(sd) + LOG2PI_F);
        }
    }

    // ---------------- block reductions ----------------
    __syncthreads();
    red[tid] = kl_acc; __syncthreads();
    for (int s2 = NTH / 2; s2 > 0; s2 >>= 1) {
        if (tid < s2) red[tid] += red[tid + s2];
        __syncthreads();
    }
    if (tid == 0) p.partials[blockIdx.x] = red[0];
    __syncthreads();
    red[tid] = nll_acc; __syncthreads();
    for (int s2 = NTH / 2; s2 > 0; s2 >>= 1) {
        if (tid < s2) red[tid] += red[tid + s2];
        __syncthreads();
    }
    if (tid == 0) p.partials[NWG + blockIdx.x] = red[0];
}

// One-time transpose of GRU weights into reduction-minor layout (coalesced reads).
__global__ void prep_transpose(const float* __restrict__ wih, const float* __restrict__ whh,
                               float* __restrict__ wihT, float* __restrict__ whhT) {
    int idx = blockIdx.x * blockDim.x + threadIdx.x;
    const int n1 = A_ * 384 * 18;
    const int n2 = A_ * 384 * 128;
    if (idx < n1) {
        int aa = idx / (384 * 18); int rem = idx - aa * 384 * 18;
        int g = rem / 18; int i = rem - g * 18;
        wihT[(aa * 18 + i) * 384 + g] = wih[idx];
    } else if (idx < n1 + n2) {
        int j = idx - n1;
        int aa = j / (384 * 128); int rem = j - aa * 384 * 128;
        int g = rem / 128; int i = rem - g * 128;
        whhT[(aa * 128 + i) * 384 + g] = whh[j];
    }
}

__global__ void finish_kernel(const float* __restrict__ partials, float* __restrict__ out) {
    __shared__ float red[256];
    int tid = threadIdx.x;
    red[tid] = (tid < NWG) ? partials[tid] : 0.f;
    __syncthreads();
    for (int s2 = 128; s2 > 0; s2 >>= 1) {
        if (tid < s2) red[tid] += red[tid + s2];
        __syncthreads();
    }
    if (tid == 0) out[0] = red[0];
    __syncthreads();
    red[tid] = (tid < NWG) ? partials[NWG + tid] : 0.f;
    __syncthreads();
    for (int s2 = 128; s2 > 0; s2 >>= 1) {
        if (tid < s2) red[tid] += red[tid + s2];
        __syncthreads();
    }
    if (tid == 0) out[1] = red[0];
}

extern "C" void kernel_launch(void* const* d_in, const int* in_sizes, int n_in,
                              void* d_out, int out_size, void* d_ws, size_t ws_size,
                              hipStream_t stream) {
    Params p;
    p.y   = (const float*)d_in[0];
    p.eps = (const float*)d_in[1];
    p.eW1 = (const float*)d_in[2];  p.eb1 = (const float*)d_in[3];
    p.eW2 = (const float*)d_in[4];  p.eb2 = (const float*)d_in[5];
    p.emW = (const float*)d_in[6];  p.emb = (const float*)d_in[7];
    p.esW = (const float*)d_in[8];  p.esb = (const float*)d_in[9];
    p.pW1 = (const float*)d_in[10]; p.pb1 = (const float*)d_in[11];
    p.pW2 = (const float*)d_in[12]; p.pb2 = (const float*)d_in[13];
    p.pmW = (const float*)d_in[14]; p.pmb = (const float*)d_in[15];
    p.psW = (const float*)d_in[16]; p.psb = (const float*)d_in[17];
    p.dW1 = (const float*)d_in[18]; p.db1 = (const float*)d_in[19];
    p.dW2 = (const float*)d_in[20]; p.db2 = (const float*)d_in[21];
    p.dmW = (const float*)d_in[22]; p.dmb = (const float*)d_in[23];
    p.dsW = (const float*)d_in[24]; p.dsb = (const float*)d_in[25];
    const float* wih = (const float*)d_in[26];
    const float* whh = (const float*)d_in[27];
    p.bih = (const float*)d_in[28]; p.bhh = (const float*)d_in[29];

    float* ws = (float*)d_ws;
    float* partials = ws;                       // 2*NWG floats
    float* wihT = ws + 512;
    float* whhT = wihT + A_ * 18 * 384;
    size_t need = (size_t)(512 + A_ * 18 * 384 + A_ * 128 * 384) * sizeof(float);
    bool tr = (ws_size >= need);
    if (tr) {
        int tot = A_ * 384 * 18 + A_ * 384 * 128;
        prep_transpose<<<(tot + 255) / 256, 256, 0, stream>>>(wih, whh, wihT, whhT);
        p.wih = wihT; p.si_ih = 384; p.sg_ih = 1;
        p.whh = whhT; p.si_hh = 384; p.sg_hh = 1;
    } else {
        p.wih = wih; p.si_ih = 1; p.sg_ih = 18;
        p.whh = whh; p.si_hh = 1; p.sg_hh = 128;
    }
    p.partials = partials;

    vrnn_kernel<<<NWG, NTH, 0, stream>>>(p);
    finish_kernel<<<1, 256, 0, stream>>>(partials, (float*)d_out);
}

// Round 2
// 1545.721 us; speedup vs baseline: 2.9191x; 2.9191x over previous
//
#include <hip/hip_runtime.h>
#include <math.h>

typedef unsigned int u32;
typedef unsigned short u16;

#define NS 128          // T-1 timesteps
#define A_ 5
#define B_ 128
#define NTH 512
#define NWG 160         // 5 agents x 32 chunks of 4 rows
#define LOG2PI_F 1.8378770664093453f

// ---- packed (uint2 = 4 f16) weight layout offsets, in uint2 units, per agent ----
#define AGU2 42752
#define OF_E1X 0
#define OF_E1Y 128
#define OF_E1H 512
#define OF_P1Y 4608
#define OF_P1H 4992
#define OF_D1Y 9088
#define OF_D1Z 9472
#define OF_D1H 9984
#define OF_EW2 14080
#define OF_PW2 18176
#define OF_DW2 22272
#define OF_EMW 26368    // em|es|pm|ps each 512
#define OF_DMW 28416    // dm|ds each 64
#define OF_IH  28544    // 5 quads x 384
#define OF_HH  30464    // 32 quads x 384

typedef _Float16 h2v __attribute__((ext_vector_type(2)));

__device__ __forceinline__ float fdot2(u32 w, u32 x, float acc) {
#if __has_builtin(__builtin_amdgcn_fdot2)
    return __builtin_amdgcn_fdot2(__builtin_bit_cast(h2v, w),
                                  __builtin_bit_cast(h2v, x), acc, false);
#else
    h2v a = __builtin_bit_cast(h2v, w), b = __builtin_bit_cast(h2v, x);
    return acc + (float)a.x * (float)b.x + (float)a.y * (float)b.y;
#endif
}

__device__ __forceinline__ u16 f2h(float f) {
    _Float16 h = (_Float16)f;
    return __builtin_bit_cast(u16, h);
}
__device__ __forceinline__ float h2f(u16 u) {
    return (float)__builtin_bit_cast(_Float16, u);
}
__device__ __forceinline__ float softplusf_(float x) {
    return fmaxf(x, 0.f) + log1pf(expf(-fabsf(x)));
}
__device__ __forceinline__ float sigmoidf_(float x) {
    return 1.f / (1.f + expf(-x));
}

struct P2 {
    const float* __restrict__ y;
    const float* __restrict__ eps;
    const float* __restrict__ eb1; const float* __restrict__ eb2;
    const float* __restrict__ pb1; const float* __restrict__ pb2;
    const float* __restrict__ db1; const float* __restrict__ db2;
    const float* __restrict__ emb; const float* __restrict__ esb;
    const float* __restrict__ pmb; const float* __restrict__ psb;
    const float* __restrict__ dmb; const float* __restrict__ dsb;
    const float* __restrict__ bih; const float* __restrict__ bhh;
    const uint2* __restrict__ wq;       // packed weights
    float* __restrict__ partials;
};

// quad-dot over a segment for 4 batch rows. x ptrs are LDS f16 rows (8B aligned).
__device__ __forceinline__ void seg4(float& a0, float& a1, float& a2, float& a3,
        const uint2* __restrict__ W, int o, int OD,
        const u16* x0, const u16* x1, const u16* x2, const u16* x3,
        int nq, int& cur, int g0, int g1) {
    int lo = g0 - cur; if (lo < 0) lo = 0;
    int hi = g1 - cur; if (hi > nq) hi = nq;
#pragma unroll 4
    for (int q = lo; q < hi; ++q) {
        uint2 w = W[q * OD + o];
        uint2 xa = *(const uint2*)(x0 + q * 4);
        uint2 xb = *(const uint2*)(x1 + q * 4);
        uint2 xc = *(const uint2*)(x2 + q * 4);
        uint2 xd = *(const uint2*)(x3 + q * 4);
        a0 = fdot2(w.x, xa.x, a0); a0 = fdot2(w.y, xa.y, a0);
        a1 = fdot2(w.x, xb.x, a1); a1 = fdot2(w.y, xb.y, a1);
        a2 = fdot2(w.x, xc.x, a2); a2 = fdot2(w.y, xc.y, a2);
        a3 = fdot2(w.x, xd.x, a3); a3 = fdot2(w.y, xd.y, a3);
    }
    cur += nq;
}

#define RED16_32(v) { v += __shfl_xor(v, 16); v += __shfl_xor(v, 32); }
#define SEL4(k, v0, v1, v2, v3) ((k)==0 ? (v0) : (k)==1 ? (v1) : (k)==2 ? (v2) : (v3))

__global__ void __launch_bounds__(NTH, 2) vrnn2(P2 p) {
    const int tid = threadIdx.x;
    const int a = blockIdx.x >> 5;          // /32
    const int b0 = (blockIdx.x & 31) * 4;
    const int wave = tid >> 6;
    const int lane = tid & 63;
    const int o = wave * 16 + (lane & 15);  // output column 0..127
    const int k4 = lane >> 4;               // K-quarter / row id 0..3

    __shared__ u16 hh_[4][128];             // h state, f16
    __shared__ u16 aA[4][128], aB[4][128], aC[4][128], aD[4][128];
    __shared__ u16 yh[4][12];               // y_t f16 (10 + 2 zero pad)
    __shared__ u16 xz[4][20];               // [x0 x1 0 0 | z16] f16
    __shared__ float xf[4][2];              // x_t fp32 for nll
    __shared__ float mue[4][16], sde[4][16], mup[4][16], sdp[4][16];
    __shared__ float dmu[4][2], dsd[4][2];
    __shared__ float bE1[128], bP1[128], bD1[128], bE2[128], bP2[128], bD2[128];
    __shared__ float bH[64];                // em|es|pm|ps x16
    __shared__ float bDH[4];                // dm|ds x2
    __shared__ float bIH[384], bHH[384];
    __shared__ float red[NTH];

    // ---- one-time preload: biases to LDS, zero pads, h=0 ----
    if (tid < 128) {
        bE1[tid] = p.eb1[a * 128 + tid]; bE2[tid] = p.eb2[a * 128 + tid];
        bP1[tid] = p.pb1[a * 128 + tid]; bP2[tid] = p.pb2[a * 128 + tid];
        bD1[tid] = p.db1[a * 128 + tid]; bD2[tid] = p.db2[a * 128 + tid];
    }
    if (tid < 64) {
        int h = tid >> 4, c = tid & 15;
        const float* s = (h == 0) ? p.emb : (h == 1) ? p.esb : (h == 2) ? p.pmb : p.psb;
        bH[tid] = s[a * 16 + c];
    }
    if (tid < 4) bDH[tid] = (tid < 2) ? p.dmb[a * 2 + tid] : p.dsb[a * 2 + (tid - 2)];
    if (tid < 384) { bIH[tid] = p.bih[a * 384 + tid]; bHH[tid] = p.bhh[a * 384 + tid]; }
    ((u16*)hh_)[tid] = 0;                    // 512 entries
    if (tid < 8) { int r = tid >> 1, c = tid & 1; yh[r][10 + c] = 0; xz[r][2 + c] = 0; }

    const uint2* WA = p.wq + (size_t)a * AGU2;

    float kl_acc = 0.f, nll_acc = 0.f;
    float hnew = 0.f;

    for (int t = 0; t < NS; ++t) {
        __syncthreads();                     // protect yh/xz/xf from prev-iter readers
        // ---- P1: load y_t, x_t ----
        if (tid < 40) {
            int r = tid / 10, j = tid - r * 10;
            yh[r][j] = f2h(p.y[t * (B_ * 10) + (b0 + r) * 10 + j]);
        } else if (tid < 48) {
            int k = tid - 40, r = k >> 1, xd = k & 1;
            float v = p.y[(t + 1) * (B_ * 10) + (b0 + r) * 10 + a * 2 + xd];
            xz[r][xd] = f2h(v); xf[r][xd] = v;
        }
        __syncthreads();

        // ---- P2: enc1 (x|y|h -> aA), pri1 (y|h -> aC) ----
        {
            float bb = (k4 == 0) ? bE1[o] : 0.f;
            float a0 = bb, a1 = bb, a2 = bb, a3 = bb;
            int cur = 0, g0 = k4 * 9, g1 = g0 + 9;      // NQ=36
            seg4(a0,a1,a2,a3, WA+OF_E1X, o,128, xz[0],xz[1],xz[2],xz[3], 1, cur,g0,g1);
            seg4(a0,a1,a2,a3, WA+OF_E1Y, o,128, yh[0],yh[1],yh[2],yh[3], 3, cur,g0,g1);
            seg4(a0,a1,a2,a3, WA+OF_E1H, o,128, hh_[0],hh_[1],hh_[2],hh_[3], 32, cur,g0,g1);
            RED16_32(a0); RED16_32(a1); RED16_32(a2); RED16_32(a3);
            float v = SEL4(k4, a0, a1, a2, a3);
            aA[k4][o] = f2h(fmaxf(v, 0.f));
        }
        {
            float bb = (k4 == 0) ? bP1[o] : 0.f;
            float a0 = bb, a1 = bb, a2 = bb, a3 = bb;
            int cur = 0, g0 = (k4 * 35) >> 2, g1 = ((k4 + 1) * 35) >> 2;  // NQ=35
            seg4(a0,a1,a2,a3, WA+OF_P1Y, o,128, yh[0],yh[1],yh[2],yh[3], 3, cur,g0,g1);
            seg4(a0,a1,a2,a3, WA+OF_P1H, o,128, hh_[0],hh_[1],hh_[2],hh_[3], 32, cur,g0,g1);
            RED16_32(a0); RED16_32(a1); RED16_32(a2); RED16_32(a3);
            float v = SEL4(k4, a0, a1, a2, a3);
            aC[k4][o] = f2h(fmaxf(v, 0.f));
        }
        __syncthreads();

        // ---- P3: enc2 (aA -> aB), pri2 (aC -> aD) ----
        {
            float bb = (k4 == 0) ? bE2[o] : 0.f;
            float a0 = bb, a1 = bb, a2 = bb, a3 = bb;
            int cur = 0, g0 = k4 * 8, g1 = g0 + 8;
            seg4(a0,a1,a2,a3, WA+OF_EW2, o,128, aA[0],aA[1],aA[2],aA[3], 32, cur,g0,g1);
            RED16_32(a0); RED16_32(a1); RED16_32(a2); RED16_32(a3);
            float v = SEL4(k4, a0, a1, a2, a3);
            aB[k4][o] = f2h(fmaxf(v, 0.f));
        }
        {
            float bb = (k4 == 0) ? bP2[o] : 0.f;
            float a0 = bb, a1 = bb, a2 = bb, a3 = bb;
            int cur = 0, g0 = k4 * 8, g1 = g0 + 8;
            seg4(a0,a1,a2,a3, WA+OF_PW2, o,128, aC[0],aC[1],aC[2],aC[3], 32, cur,g0,g1);
            RED16_32(a0); RED16_32(a1); RED16_32(a2); RED16_32(a3);
            float v = SEL4(k4, a0, a1, a2, a3);
            aD[k4][o] = f2h(fmaxf(v, 0.f));
        }
        __syncthreads();

        // ---- P4: 4 gaussian heads (128->16), 2 rows per item ----
        {
            int zd = lane & 15;
            int head = wave & 3;            // 0 em, 1 es, 2 pm, 3 ps
            int rh = wave >> 2;             // row half
            int r0 = 2 * rh, r1 = r0 + 1;
            const u16* s0 = (head < 2) ? aB[r0] : aD[r0];
            const u16* s1 = (head < 2) ? aB[r1] : aD[r1];
            const uint2* W = WA + OF_EMW + head * 512;
            float bb = (k4 == 0) ? bH[head * 16 + zd] : 0.f;
            float e0 = bb, e1 = bb;
            int q0 = k4 * 8;
#pragma unroll 4
            for (int q = q0; q < q0 + 8; ++q) {
                uint2 w = W[q * 16 + zd];
                uint2 xa = *(const uint2*)(s0 + q * 4);
                uint2 xb = *(const uint2*)(s1 + q * 4);
                e0 = fdot2(w.x, xa.x, e0); e0 = fdot2(w.y, xa.y, e0);
                e1 = fdot2(w.x, xb.x, e1); e1 = fdot2(w.y, xb.y, e1);
            }
            RED16_32(e0); RED16_32(e1);
            if (k4 < 2) {
                float v = (k4 == 0) ? e0 : e1;
                int r = r0 + k4;
                if (head == 0) mue[r][zd] = v;
                else if (head == 1) sde[r][zd] = softplusf_(v);
                else if (head == 2) mup[r][zd] = v;
                else sdp[r][zd] = softplusf_(v);
            }
        }
        __syncthreads();

        // ---- P5: z sample + KL ----
        if (tid < 64) {
            int r = tid >> 4, zd = tid & 15;
            float em = mue[r][zd], es = sde[r][zd], pm = mup[r][zd], ps = sdp[r][zd];
            float e = p.eps[(((size_t)t * A_ + a) * B_ + (b0 + r)) * 16 + zd];
            float zv = fmaf(e, es, em);
            xz[r][4 + zd] = f2h(zv);
            float dm = em - pm;
            kl_acc += 0.5f * (2.f * (logf(ps) - logf(es)) + (es * es + dm * dm) / (ps * ps) - 1.f);
        }
        __syncthreads();

        // ---- P6: dec1 (y|z|h -> aA)  +  GRU dots & gate math (h write deferred) ----
        {
            float bb = (k4 == 0) ? bD1[o] : 0.f;
            float a0 = bb, a1 = bb, a2 = bb, a3 = bb;
            int cur = 0, g0 = (k4 * 39) >> 2, g1 = ((k4 + 1) * 39) >> 2;  // NQ=39
            seg4(a0,a1,a2,a3, WA+OF_D1Y, o,128, yh[0],yh[1],yh[2],yh[3], 3, cur,g0,g1);
            seg4(a0,a1,a2,a3, WA+OF_D1Z, o,128, &xz[0][4],&xz[1][4],&xz[2][4],&xz[3][4], 4, cur,g0,g1);
            seg4(a0,a1,a2,a3, WA+OF_D1H, o,128, hh_[0],hh_[1],hh_[2],hh_[3], 32, cur,g0,g1);
            RED16_32(a0); RED16_32(a1); RED16_32(a2); RED16_32(a3);
            float v = SEL4(k4, a0, a1, a2, a3);
            aA[k4][o] = f2h(fmaxf(v, 0.f));
        }
        {
            // GRU: gates g = o, 128+o, 256+o over input [x|z] (5 quads) and h (32 quads)
            float gi0[4], gi1[4], gi2[4], gh0[4], gh1[4], gh2[4];
            float bi0 = (k4 == 0) ? bIH[o] : 0.f;
            float bi1 = (k4 == 0) ? bIH[128 + o] : 0.f;
            float bi2 = (k4 == 0) ? bIH[256 + o] : 0.f;
            float bh0 = (k4 == 0) ? bHH[o] : 0.f;
            float bh1 = (k4 == 0) ? bHH[128 + o] : 0.f;
            float bh2 = (k4 == 0) ? bHH[256 + o] : 0.f;
#pragma unroll
            for (int r = 0; r < 4; ++r) {
                gi0[r] = bi0; gi1[r] = bi1; gi2[r] = bi2;
                gh0[r] = bh0; gh1[r] = bh1; gh2[r] = bh2;
            }
            int g0 = (k4 * 37) >> 2, g1 = ((k4 + 1) * 37) >> 2;   // NQ=37
            {   // ih quads: global [0,5)
                int lo = g0 > 5 ? 5 : g0, hi = g1 > 5 ? 5 : g1;
#pragma unroll 2
                for (int q = lo; q < hi; ++q) {
                    const uint2* Wq = WA + OF_IH + q * 384;
                    uint2 w0 = Wq[o], w1 = Wq[128 + o], w2 = Wq[256 + o];
#pragma unroll
                    for (int r = 0; r < 4; ++r) {
                        uint2 xv = *(const uint2*)(&xz[r][0] + q * 4);
                        gi0[r] = fdot2(w0.x, xv.x, gi0[r]); gi0[r] = fdot2(w0.y, xv.y, gi0[r]);
                        gi1[r] = fdot2(w1.x, xv.x, gi1[r]); gi1[r] = fdot2(w1.y, xv.y, gi1[r]);
                        gi2[r] = fdot2(w2.x, xv.x, gi2[r]); gi2[r] = fdot2(w2.y, xv.y, gi2[r]);
                    }
                }
            }
            {   // hh quads: global [5,37) -> local [0,32)
                int lo = g0 - 5; if (lo < 0) lo = 0;
                int hi = g1 - 5; if (hi > 32) hi = 32;
#pragma unroll 4
                for (int q = lo; q < hi; ++q) {
                    const uint2* Wq = WA + OF_HH + q * 384;
                    uint2 w0 = Wq[o], w1 = Wq[128 + o], w2 = Wq[256 + o];
#pragma unroll
                    for (int r = 0; r < 4; ++r) {
                        uint2 xv = *(const uint2*)(hh_[r] + q * 4);
                        gh0[r] = fdot2(w0.x, xv.x, gh0[r]); gh0[r] = fdot2(w0.y, xv.y, gh0[r]);
                        gh1[r] = fdot2(w1.x, xv.x, gh1[r]); gh1[r] = fdot2(w1.y, xv.y, gh1[r]);
                        gh2[r] = fdot2(w2.x, xv.x, gh2[r]); gh2[r] = fdot2(w2.y, xv.y, gh2[r]);
                    }
                }
            }
            float s0[4], s1[4];
#pragma unroll
            for (int r = 0; r < 4; ++r) {
                s0[r] = gi0[r] + gh0[r]; s1[r] = gi1[r] + gh1[r];
                RED16_32(s0[r]); RED16_32(s1[r]); RED16_32(gi2[r]); RED16_32(gh2[r]);
            }
            float rs = SEL4(k4, s0[0], s0[1], s0[2], s0[3]);
            float zs = SEL4(k4, s1[0], s1[1], s1[2], s1[3]);
            float in2 = SEL4(k4, gi2[0], gi2[1], gi2[2], gi2[3]);
            float hn2 = SEL4(k4, gh2[0], gh2[1], gh2[2], gh2[3]);
            float rr = sigmoidf_(rs);
            float zz = sigmoidf_(zs);
            float nn = tanhf(fmaf(rr, hn2, in2));
            float hold = h2f(hh_[k4][o]);
            hnew = fmaf(zz, hold - nn, nn);          // (1-z)*n + z*h
        }
        __syncthreads();

        // ---- P7: dec2 (aA -> aB) ----
        {
            float bb = (k4 == 0) ? bD2[o] : 0.f;
            float a0 = bb, a1 = bb, a2 = bb, a3 = bb;
            int cur = 0, g0 = k4 * 8, g1 = g0 + 8;
            seg4(a0,a1,a2,a3, WA+OF_DW2, o,128, aA[0],aA[1],aA[2],aA[3], 32, cur,g0,g1);
            RED16_32(a0); RED16_32(a1); RED16_32(a2); RED16_32(a3);
            float v = SEL4(k4, a0, a1, a2, a3);
            aB[k4][o] = f2h(fmaxf(v, 0.f));
        }
        __syncthreads();

        // ---- P8: dec heads (128->2) + h state write ----
        hh_[k4][o] = f2h(hnew);
        {
            int out = tid >> 5, part = tid & 31;    // 16 outputs x 32-way K split
            int head = out >> 3, sub = out & 7, r = sub >> 1, xd = sub & 1;
            const uint2* W = WA + OF_DMW + head * 64;
            uint2 w = W[part * 2 + xd];
            uint2 xa = *(const uint2*)(aB[r] + part * 4);
            float s = fdot2(w.x, xa.x, 0.f);
            s = fdot2(w.y, xa.y, s);
            s += __shfl_xor(s, 1); s += __shfl_xor(s, 2); s += __shfl_xor(s, 4);
            s += __shfl_xor(s, 8); s += __shfl_xor(s, 16);
            if (part == 0) {
                float v = bDH[head * 2 + xd] + s;
                if (head) dsd[r][xd] = softplusf_(v);
                else dmu[r][xd] = v;
            }
        }
        __syncthreads();

        // ---- P9: NLL ----
        if (tid < 8) {
            int r = tid >> 1, xd = tid & 1;
            float d = xf[r][xd] - dmu[r][xd];
            float sd = dsd[r][xd];
            nll_acc += 0.5f * (d * d / (sd * sd) + 2.f * logf(sd) + LOG2PI_F);
        }
    }

    // ---- block reductions ----
    __syncthreads();
    red[tid] = kl_acc; __syncthreads();
    for (int s2 = NTH / 2; s2 > 0; s2 >>= 1) {
        if (tid < s2) red[tid] += red[tid + s2];
        __syncthreads();
    }
    if (tid == 0) p.partials[blockIdx.x] = red[0];
    __syncthreads();
    red[tid] = nll_acc; __syncthreads();
    for (int s2 = NTH / 2; s2 > 0; s2 >>= 1) {
        if (tid < s2) red[tid] += red[tid + s2];
        __syncthreads();
    }
    if (tid == 0) p.partials[NWG + blockIdx.x] = red[0];
}

// ---------------- prep: pack all weights to f16x4 quads ----------------
struct PrepP {
    const float* src[14];
    uint2* dst;
};

__global__ void prep_pack(PrepP pp) {
    const int jsrc[20] = {0,0,0, 1,1, 2,2,2, 3,4,5, 6,7,8,9, 10,11, 12,12,13};
    const int jrow0[20]= {0,2,12, 0,10, 0,10,26, 0,0,0, 0,0,0,0, 0,0, 0,2,0};
    const int jnk[20]  = {2,10,128, 10,128, 10,16,128, 128,128,128, 128,128,128,128, 128,128, 2,16,128};
    const int jnq[20]  = {1,3,32, 3,32, 3,4,32, 32,32,32, 32,32,32,32, 32,32, 1,4,32};
    const int jod[20]  = {128,128,128, 128,128, 128,128,128, 128,128,128, 16,16,16,16, 2,2, 384,384,384};
    const int jdst[20] = {OF_E1X,OF_E1Y,OF_E1H, OF_P1Y,OF_P1H, OF_D1Y,OF_D1Z,OF_D1H,
                          OF_EW2,OF_PW2,OF_DW2,
                          OF_EMW,OF_EMW+512,OF_EMW+1024,OF_EMW+1536,
                          OF_DMW,OF_DMW+64, OF_IH,OF_IH+384,OF_HH};
    const int jkt[20]  = {140,140,140, 138,138, 154,154,154, 128,128,128, 128,128,128,128, 128,128, 18,18,128};
    const int jkb[20]  = {0,0,0,0,0,0,0,0,0,0,0,0,0,0,0,0,0,1,1,1};

    int job = blockIdx.y;
    int nq = jnq[job], od = jod[job];
    int total = A_ * nq * od;
    int idx = blockIdx.x * 256 + threadIdx.x;
    if (idx >= total) return;
    int a = idx / (nq * od);
    int rem = idx - a * (nq * od);
    int q = rem / od;
    int c = rem - q * od;
    const float* s = pp.src[jsrc[job]];
    int row0 = jrow0[job], nk = jnk[job], kt = jkt[job];
    float v[4];
#pragma unroll
    for (int i = 0; i < 4; ++i) {
        int k = 4 * q + i;
        if (k < nk) {
            if (jkb[job]) v[i] = s[((size_t)a * 384 + c) * kt + row0 + k];      // GRU: [a][g][k]
            else          v[i] = s[((size_t)a * kt + row0 + k) * od + c];       // [a][k][od]
        } else v[i] = 0.f;
    }
    u32 lo = (u32)f2h(v[0]) | ((u32)f2h(v[1]) << 16);
    u32 hi = (u32)f2h(v[2]) | ((u32)f2h(v[3]) << 16);
    pp.dst[(size_t)a * AGU2 + jdst[job] + q * od + c] = make_uint2(lo, hi);
}

__global__ void finish_kernel(const float* __restrict__ partials, float* __restrict__ out) {
    __shared__ float red[256];
    int tid = threadIdx.x;
    red[tid] = (tid < NWG) ? partials[tid] : 0.f;
    __syncthreads();
    for (int s2 = 128; s2 > 0; s2 >>= 1) {
        if (tid < s2) red[tid] += red[tid + s2];
        __syncthreads();
    }
    if (tid == 0) out[0] = red[0];
    __syncthreads();
    red[tid] = (tid < NWG) ? partials[NWG + tid] : 0.f;
    __syncthreads();
    for (int s2 = 128; s2 > 0; s2 >>= 1) {
        if (tid < s2) red[tid] += red[tid + s2];
        __syncthreads();
    }
    if (tid == 0) out[1] = red[0];
}

extern "C" void kernel_launch(void* const* d_in, const int* in_sizes, int n_in,
                              void* d_out, int out_size, void* d_ws, size_t ws_size,
                              hipStream_t stream) {
    float* partials = (float*)d_ws;                         // 320 floats
    uint2* wq = (uint2*)((char*)d_ws + 4096);               // packed weights, 1.71 MB

    PrepP pp;
    pp.src[0]  = (const float*)d_in[2];   // eW1
    pp.src[1]  = (const float*)d_in[10];  // pW1
    pp.src[2]  = (const float*)d_in[18];  // dW1
    pp.src[3]  = (const float*)d_in[4];   // eW2
    pp.src[4]  = (const float*)d_in[12];  // pW2
    pp.src[5]  = (const float*)d_in[20];  // dW2
    pp.src[6]  = (const float*)d_in[6];   // emW
    pp.src[7]  = (const float*)d_in[8];   // esW
    pp.src[8]  = (const float*)d_in[14];  // pmW
    pp.src[9]  = (const float*)d_in[16];  // psW
    pp.src[10] = (const float*)d_in[22];  // dmW
    pp.src[11] = (const float*)d_in[24];  // dsW
    pp.src[12] = (const float*)d_in[26];  // wih
    pp.src[13] = (const float*)d_in[27];  // whh
    pp.dst = wq;
    // max job total = 5*32*384 = 61440 -> 240 blocks of 256, y = 20 jobs
    prep_pack<<<dim3(240, 20), 256, 0, stream>>>(pp);

    P2 p;
    p.y   = (const float*)d_in[0];
    p.eps = (const float*)d_in[1];
    p.eb1 = (const float*)d_in[3];  p.eb2 = (const float*)d_in[5];
    p.emb = (const float*)d_in[7];  p.esb = (const float*)d_in[9];
    p.pb1 = (const float*)d_in[11]; p.pb2 = (const float*)d_in[13];
    p.pmb = (const float*)d_in[15]; p.psb = (const float*)d_in[17];
    p.db1 = (const float*)d_in[19]; p.db2 = (const float*)d_in[21];
    p.dmb = (const float*)d_in[23]; p.dsb = (const float*)d_in[25];
    p.bih = (const float*)d_in[28]; p.bhh = (const float*)d_in[29];
    p.wq = wq;
    p.partials = partials;

    vrnn2<<<NWG, NTH, 0, stream>>>(p);
    finish_kernel<<<1, 256, 0, stream>>>(partials, (float*)d_out);
}

// Round 3
// 1092.670 us; speedup vs baseline: 4.1295x; 1.4146x over previous
//
#include <hip/hip_runtime.h>
#include <math.h>

typedef unsigned int u32;
typedef unsigned short u16;

#define NS 128          // T-1 timesteps
#define A_ 5
#define B_ 128
#define NTH 512
#define NWG 160         // 5 agents x 32 chunks of 4 rows
#define LOG2PI_F 1.8378770664093453f

// ---- packed weight layout (uint2 = 4 f16 units), per agent ----
// U-layers use the unified 160-elem input [x2 y10 z16 pad4 h128] = 40 quads,
// with zero weights where a layer doesn't consume a slot.
#define OF_E1 0         // 40q x 128
#define OF_P1 5120
#define OF_D1 10240
#define OF_G  15360     // 40q x 384 (3 gates x 128)
#define OF_E2 30720     // 32q x 128
#define OF_P2 34816
#define OF_D2 38912
#define OF_H  43008     // 4 heads x (32q x 16)
#define OF_DH 45056     // 2 heads x (32q x 2)
#define AGU2  45184

typedef _Float16 half2v __attribute__((ext_vector_type(2)));

__device__ __forceinline__ float fdot2(u32 w, u32 x, float acc) {
#if __has_builtin(__builtin_amdgcn_fdot2)
    return __builtin_amdgcn_fdot2(__builtin_bit_cast(half2v, w),
                                  __builtin_bit_cast(half2v, x), acc, false);
#else
    half2v a = __builtin_bit_cast(half2v, w), b = __builtin_bit_cast(half2v, x);
    return acc + (float)a.x * (float)b.x + (float)a.y * (float)b.y;
#endif
}
__device__ __forceinline__ u16 f2h(float f) { _Float16 h = (_Float16)f; return __builtin_bit_cast(u16, h); }
__device__ __forceinline__ float h2f(u16 u) { return (float)__builtin_bit_cast(_Float16, u); }
__device__ __forceinline__ float softplusf_(float x) { return fmaxf(x, 0.f) + log1pf(expf(-fabsf(x))); }
__device__ __forceinline__ float sigmoidf_(float x) { return 1.f / (1.f + expf(-x)); }

#define RED16_32(v) { v += __shfl_xor(v, 16); v += __shfl_xor(v, 32); }
#define SEL4(k, v0, v1, v2, v3) ((k)==0 ? (v0) : (k)==1 ? (v1) : (k)==2 ? (v2) : (v3))

struct P3s {
    const float* __restrict__ y;
    const float* __restrict__ eps;
    const float* __restrict__ eb1; const float* __restrict__ eb2;
    const float* __restrict__ pb1; const float* __restrict__ pb2;
    const float* __restrict__ db1; const float* __restrict__ db2;
    const float* __restrict__ emb; const float* __restrict__ esb;
    const float* __restrict__ pmb; const float* __restrict__ psb;
    const float* __restrict__ dmb; const float* __restrict__ dsb;
    const float* __restrict__ bih; const float* __restrict__ bhh;
    const uint2* __restrict__ wq;
    float* __restrict__ partials;
};

__global__ void __launch_bounds__(NTH, 2) vrnn3(P3s p) {
    const int tid = threadIdx.x;
    const int a = blockIdx.x >> 5;
    const int b0 = (blockIdx.x & 31) * 4;
    const int wave = tid >> 6;
    const int lane = tid & 63;
    const int o = wave * 16 + (lane & 15);   // output column 0..127
    const int k4 = lane >> 4;                // K-quarter / row id 0..3
    const bool k0 = (k4 == 0);

    __shared__ __align__(16) u16 U[4][160];          // [x2 y10 z16 pad4 h128]
    __shared__ __align__(16) u16 aA[4][128], aB[4][128], aC[4][128], aD[4][128];
    __shared__ float mue[4][16], sde[4][16], mup[4][16], sdp[4][16];
    __shared__ float xf[4][2], dmu[4][2], dsd[4][2];
    __shared__ uint2 whLDS[2048];   // 4 heads x 32q x 16
    __shared__ uint2 wdhLDS[128];   // 2 heads x 32q x 2
    __shared__ float red[NTH];

    const uint2* WA = p.wq + (size_t)a * AGU2;

    // ---- init LDS: zero U (pad + h), copy head weights ----
    for (int i = tid; i < 4 * 160; i += NTH) (&U[0][0])[i] = 0;
    for (int i = tid; i < 2048; i += NTH) whLDS[i] = WA[OF_H + i];
    if (tid < 128) wdhLDS[tid] = WA[OF_DH + tid];

    // ---- register-resident weights (loop-invariant) ----
    uint2 wE1[10], wP1[10], wD1[10], wG0[10], wG1[10], wG2[10];
    uint2 wE2[8], wP2[8], wD2[8];
#pragma unroll
    for (int j = 0; j < 10; ++j) {
        int q = k4 * 10 + j;
        wE1[j] = WA[OF_E1 + q * 128 + o];
        wP1[j] = WA[OF_P1 + q * 128 + o];
        wD1[j] = WA[OF_D1 + q * 128 + o];
        wG0[j] = WA[OF_G + q * 384 + o];
        wG1[j] = WA[OF_G + q * 384 + 128 + o];
        wG2[j] = WA[OF_G + q * 384 + 256 + o];
    }
#pragma unroll
    for (int j = 0; j < 8; ++j) {
        int q = k4 * 8 + j;
        wE2[j] = WA[OF_E2 + q * 128 + o];
        wP2[j] = WA[OF_P2 + q * 128 + o];
        wD2[j] = WA[OF_D2 + q * 128 + o];
    }

    // ---- register-resident biases ----
    const float rbE1 = p.eb1[a * 128 + o], rbE2 = p.eb2[a * 128 + o];
    const float rbP1 = p.pb1[a * 128 + o], rbP2 = p.pb2[a * 128 + o];
    const float rbD1 = p.db1[a * 128 + o], rbD2 = p.db2[a * 128 + o];
    const float rbI0 = p.bih[a * 384 + o], rbI1 = p.bih[a * 384 + 128 + o], rbI2 = p.bih[a * 384 + 256 + o];
    const float rbH0 = p.bhh[a * 384 + o], rbH1 = p.bhh[a * 384 + 128 + o], rbH2 = p.bhh[a * 384 + 256 + o];
    const int headH = wave & 3, zdH = lane & 15, rH = (wave >> 2) * 2;
    const float rbH = ((headH == 0) ? p.emb : (headH == 1) ? p.esb
                     : (headH == 2) ? p.pmb : p.psb)[a * 16 + zdH];
    const int outD = tid >> 5, partD = tid & 31;
    const int headD = outD >> 3, subD = outD & 7, rD = subD >> 1, xdD = subD & 1;
    const float rbDH = (headD ? p.dsb : p.dmb)[a * 2 + xdD];

    // ---- per-row LDS base pointers (k4-offset folded in) ----
    const u16* Ub[4];  const u16* aAb[4]; const u16* aBb[4]; const u16* aCb[4]; const u16* aDb[4];
#pragma unroll
    for (int r = 0; r < 4; ++r) {
        Ub[r]  = &U[r][0]  + k4 * 40;   // 10 quads * 4 u16
        aAb[r] = &aA[r][0] + k4 * 32;   // 8 quads * 4 u16
        aBb[r] = &aB[r][0] + k4 * 32;
        aCb[r] = &aC[r][0] + k4 * 32;
        aDb[r] = &aD[r][0] + k4 * 32;
    }

    // ---- prefetch t=0 inputs into registers ----
    const int ry = tid / 10, jy = tid - ry * 10;            // tid<40
    const int rx = (tid - 40) >> 1, xdx = (tid - 40) & 1;   // 40<=tid<48
    const int re = tid >> 4, ze = tid & 15;                 // tid<64
    float ypre = 0.f, xpre = 0.f, epre = 0.f;
    if (tid < 40) ypre = p.y[0 * (B_ * 10) + (b0 + ry) * 10 + jy];
    else if (tid < 48) xpre = p.y[1 * (B_ * 10) + (b0 + rx) * 10 + a * 2 + xdx];
    if (tid < 64) epre = p.eps[(((size_t)0 * A_ + a) * B_ + (b0 + re)) * 16 + ze];

    float kl_acc = 0.f, nll_acc = 0.f, hnew = 0.f;

#pragma unroll 1
    for (int t = 0; t < NS; ++t) {
        const int tn = (t + 1 < NS) ? t + 1 : t;
        __syncthreads();
        // ---- P1: commit prefetched inputs, issue next prefetch ----
        if (tid < 40) {
            U[ry][2 + jy] = f2h(ypre);
            ypre = p.y[tn * (B_ * 10) + (b0 + ry) * 10 + jy];
        } else if (tid < 48) {
            U[rx][xdx] = f2h(xpre); xf[rx][xdx] = xpre;
            xpre = p.y[(tn + 1) * (B_ * 10) + (b0 + rx) * 10 + a * 2 + xdx];
        }
        __syncthreads();

        // ---- P2: enc1 + pri1 (shared U reads) ----
        {
            float aE[4], aP[4];
#pragma unroll
            for (int r = 0; r < 4; ++r) { aE[r] = k0 ? rbE1 : 0.f; aP[r] = k0 ? rbP1 : 0.f; }
#pragma unroll
            for (int pp = 0; pp < 5; ++pp) {
#pragma unroll
                for (int r = 0; r < 4; ++r) {
                    uint4 xv = *(const uint4*)(Ub[r] + pp * 8);
                    aE[r] = fdot2(wE1[2*pp].x,   xv.x, aE[r]);
                    aE[r] = fdot2(wE1[2*pp].y,   xv.y, aE[r]);
                    aE[r] = fdot2(wE1[2*pp+1].x, xv.z, aE[r]);
                    aE[r] = fdot2(wE1[2*pp+1].y, xv.w, aE[r]);
                    aP[r] = fdot2(wP1[2*pp].x,   xv.x, aP[r]);
                    aP[r] = fdot2(wP1[2*pp].y,   xv.y, aP[r]);
                    aP[r] = fdot2(wP1[2*pp+1].x, xv.z, aP[r]);
                    aP[r] = fdot2(wP1[2*pp+1].y, xv.w, aP[r]);
                }
            }
#pragma unroll
            for (int r = 0; r < 4; ++r) { RED16_32(aE[r]); RED16_32(aP[r]); }
            float vE = SEL4(k4, aE[0], aE[1], aE[2], aE[3]);
            float vP = SEL4(k4, aP[0], aP[1], aP[2], aP[3]);
            aA[k4][o] = f2h(fmaxf(vE, 0.f));
            aC[k4][o] = f2h(fmaxf(vP, 0.f));
        }
        __syncthreads();

        // ---- P3: enc2 (aA->aB), pri2 (aC->aD) ----
        {
            float aE[4], aP[4];
#pragma unroll
            for (int r = 0; r < 4; ++r) { aE[r] = k0 ? rbE2 : 0.f; aP[r] = k0 ? rbP2 : 0.f; }
#pragma unroll
            for (int pp = 0; pp < 4; ++pp) {
#pragma unroll
                for (int r = 0; r < 4; ++r) {
                    uint4 xa = *(const uint4*)(aAb[r] + pp * 8);
                    uint4 xc = *(const uint4*)(aCb[r] + pp * 8);
                    aE[r] = fdot2(wE2[2*pp].x,   xa.x, aE[r]);
                    aE[r] = fdot2(wE2[2*pp].y,   xa.y, aE[r]);
                    aE[r] = fdot2(wE2[2*pp+1].x, xa.z, aE[r]);
                    aE[r] = fdot2(wE2[2*pp+1].y, xa.w, aE[r]);
                    aP[r] = fdot2(wP2[2*pp].x,   xc.x, aP[r]);
                    aP[r] = fdot2(wP2[2*pp].y,   xc.y, aP[r]);
                    aP[r] = fdot2(wP2[2*pp+1].x, xc.z, aP[r]);
                    aP[r] = fdot2(wP2[2*pp+1].y, xc.w, aP[r]);
                }
            }
#pragma unroll
            for (int r = 0; r < 4; ++r) { RED16_32(aE[r]); RED16_32(aP[r]); }
            float vE = SEL4(k4, aE[0], aE[1], aE[2], aE[3]);
            float vP = SEL4(k4, aP[0], aP[1], aP[2], aP[3]);
            aB[k4][o] = f2h(fmaxf(vE, 0.f));
            aD[k4][o] = f2h(fmaxf(vP, 0.f));
        }
        __syncthreads();

        // ---- P4: 4 gaussian heads (128->16), weights from LDS ----
        {
            const u16* s0p = ((headH < 2) ? aBb[rH]     - k4*32 : aDb[rH]     - k4*32) + k4*32;
            const u16* s1p = ((headH < 2) ? aBb[rH + 1] - k4*32 : aDb[rH + 1] - k4*32) + k4*32;
            float e0 = k0 ? rbH : 0.f, e1 = k0 ? rbH : 0.f;
#pragma unroll
            for (int pp = 0; pp < 4; ++pp) {
                int q = k4 * 8 + 2 * pp;
                uint2 w0 = whLDS[headH * 512 + q * 16 + zdH];
                uint2 w1 = whLDS[headH * 512 + (q + 1) * 16 + zdH];
                uint4 x0 = *(const uint4*)(s0p + pp * 8);
                uint4 x1 = *(const uint4*)(s1p + pp * 8);
                e0 = fdot2(w0.x, x0.x, e0); e0 = fdot2(w0.y, x0.y, e0);
                e0 = fdot2(w1.x, x0.z, e0); e0 = fdot2(w1.y, x0.w, e0);
                e1 = fdot2(w0.x, x1.x, e1); e1 = fdot2(w0.y, x1.y, e1);
                e1 = fdot2(w1.x, x1.z, e1); e1 = fdot2(w1.y, x1.w, e1);
            }
            RED16_32(e0); RED16_32(e1);
            if (k4 < 2) {
                float v = (k4 == 0) ? e0 : e1;
                int r = rH + k4;
                if (headH == 0)      mue[r][zdH] = v;
                else if (headH == 1) sde[r][zdH] = softplusf_(v);
                else if (headH == 2) mup[r][zdH] = v;
                else                 sdp[r][zdH] = softplusf_(v);
            }
        }
        __syncthreads();

        // ---- P5: z sample + KL (eps was prefetched) ----
        if (tid < 64) {
            float em = mue[re][ze], es = sde[re][ze], pm = mup[re][ze], ps = sdp[re][ze];
            float zv = fmaf(epre, es, em);
            U[re][12 + ze] = f2h(zv);
            float dm = em - pm;
            kl_acc += 0.5f * (2.f * (logf(ps) - logf(es)) + (es * es + dm * dm) / (ps * ps) - 1.f);
            epre = p.eps[(((size_t)tn * A_ + a) * B_ + (b0 + re)) * 16 + ze];
        }
        __syncthreads();

        // ---- P6: dec1 + GRU (shared U reads) ----
        {
            float aO[4], s0[4], s1[4], g2a[4], g2b[4];
#pragma unroll
            for (int r = 0; r < 4; ++r) {
                aO[r]  = k0 ? rbD1 : 0.f;
                s0[r]  = k0 ? (rbI0 + rbH0) : 0.f;
                s1[r]  = k0 ? (rbI1 + rbH1) : 0.f;
                g2a[r] = k0 ? rbI2 : 0.f;
                g2b[r] = k0 ? rbH2 : 0.f;
            }
#pragma unroll
            for (int pp = 0; pp < 5; ++pp) {
#pragma unroll
                for (int r = 0; r < 4; ++r) {
                    uint4 xv = *(const uint4*)(Ub[r] + pp * 8);
                    aO[r] = fdot2(wD1[2*pp].x,   xv.x, aO[r]);
                    aO[r] = fdot2(wD1[2*pp].y,   xv.y, aO[r]);
                    aO[r] = fdot2(wD1[2*pp+1].x, xv.z, aO[r]);
                    aO[r] = fdot2(wD1[2*pp+1].y, xv.w, aO[r]);
                    s0[r] = fdot2(wG0[2*pp].x,   xv.x, s0[r]);
                    s0[r] = fdot2(wG0[2*pp].y,   xv.y, s0[r]);
                    s0[r] = fdot2(wG0[2*pp+1].x, xv.z, s0[r]);
                    s0[r] = fdot2(wG0[2*pp+1].y, xv.w, s0[r]);
                    s1[r] = fdot2(wG1[2*pp].x,   xv.x, s1[r]);
                    s1[r] = fdot2(wG1[2*pp].y,   xv.y, s1[r]);
                    s1[r] = fdot2(wG1[2*pp+1].x, xv.z, s1[r]);
                    s1[r] = fdot2(wG1[2*pp+1].y, xv.w, s1[r]);
                    // gate-2: pairs 0-3 cover u<32 (ih region for k4==0), pair 4 covers h
                    float& g2 = (pp < 4) ? g2a[r] : g2b[r];
                    g2 = fdot2(wG2[2*pp].x,   xv.x, g2);
                    g2 = fdot2(wG2[2*pp].y,   xv.y, g2);
                    g2 = fdot2(wG2[2*pp+1].x, xv.z, g2);
                    g2 = fdot2(wG2[2*pp+1].y, xv.w, g2);
                }
            }
            float gi2[4], gh2[4];
#pragma unroll
            for (int r = 0; r < 4; ++r) {
                gi2[r] = k0 ? g2a[r] : 0.f;
                gh2[r] = k0 ? g2b[r] : (g2a[r] + g2b[r]);
            }
#pragma unroll
            for (int r = 0; r < 4; ++r) {
                RED16_32(aO[r]); RED16_32(s0[r]); RED16_32(s1[r]);
                RED16_32(gi2[r]); RED16_32(gh2[r]);
            }
            float vD = SEL4(k4, aO[0], aO[1], aO[2], aO[3]);
            float rs = SEL4(k4, s0[0], s0[1], s0[2], s0[3]);
            float zs = SEL4(k4, s1[0], s1[1], s1[2], s1[3]);
            float i2 = SEL4(k4, gi2[0], gi2[1], gi2[2], gi2[3]);
            float hh2 = SEL4(k4, gh2[0], gh2[1], gh2[2], gh2[3]);
            float rr = sigmoidf_(rs);
            float zz = sigmoidf_(zs);
            float nn = tanhf(fmaf(rr, hh2, i2));
            float hold = h2f(U[k4][32 + o]);
            hnew = fmaf(zz, hold - nn, nn);
            aA[k4][o] = f2h(fmaxf(vD, 0.f));
        }
        __syncthreads();

        // ---- P7: dec2 (aA -> aB) ----
        {
            float aE[4];
#pragma unroll
            for (int r = 0; r < 4; ++r) aE[r] = k0 ? rbD2 : 0.f;
#pragma unroll
            for (int pp = 0; pp < 4; ++pp) {
#pragma unroll
                for (int r = 0; r < 4; ++r) {
                    uint4 xa = *(const uint4*)(aAb[r] + pp * 8);
                    aE[r] = fdot2(wD2[2*pp].x,   xa.x, aE[r]);
                    aE[r] = fdot2(wD2[2*pp].y,   xa.y, aE[r]);
                    aE[r] = fdot2(wD2[2*pp+1].x, xa.z, aE[r]);
                    aE[r] = fdot2(wD2[2*pp+1].y, xa.w, aE[r]);
                }
            }
#pragma unroll
            for (int r = 0; r < 4; ++r) RED16_32(aE[r]);
            float vE = SEL4(k4, aE[0], aE[1], aE[2], aE[3]);
            aB[k4][o] = f2h(fmaxf(vE, 0.f));
        }
        __syncthreads();

        // ---- P8: h write + dec heads (128->2) ----
        U[k4][32 + o] = f2h(hnew);
        {
            uint2 w = wdhLDS[headD * 64 + partD * 2 + xdD];
            uint2 xa = *(const uint2*)(&aB[rD][0] + partD * 4);
            float s = fdot2(w.x, xa.x, 0.f);
            s = fdot2(w.y, xa.y, s);
            s += __shfl_xor(s, 1); s += __shfl_xor(s, 2); s += __shfl_xor(s, 4);
            s += __shfl_xor(s, 8); s += __shfl_xor(s, 16);
            if (partD == 0) {
                float v = rbDH + s;
                if (headD) dsd[rD][xdD] = softplusf_(v);
                else       dmu[rD][xdD] = v;
            }
        }
        __syncthreads();

        // ---- P9: NLL ----
        if (tid < 8) {
            int r = tid >> 1, xd = tid & 1;
            float d = xf[r][xd] - dmu[r][xd];
            float sd = dsd[r][xd];
            nll_acc += 0.5f * (d * d / (sd * sd) + 2.f * logf(sd) + LOG2PI_F);
        }
    }

    // ---- block reductions ----
    __syncthreads();
    red[tid] = kl_acc; __syncthreads();
    for (int s2 = NTH / 2; s2 > 0; s2 >>= 1) {
        if (tid < s2) red[tid] += red[tid + s2];
        __syncthreads();
    }
    if (tid == 0) p.partials[blockIdx.x] = red[0];
    __syncthreads();
    red[tid] = nll_acc; __syncthreads();
    for (int s2 = NTH / 2; s2 > 0; s2 >>= 1) {
        if (tid < s2) red[tid] += red[tid + s2];
        __syncthreads();
    }
    if (tid == 0) p.partials[NWG + blockIdx.x] = red[0];
}

// ---------------- prep: pack weights into unified zero-padded f16 quads ----------------
struct PrepP {
    const float* eW1; const float* pW1; const float* dW1;
    const float* wih; const float* whh;
    const float* eW2; const float* pW2; const float* dW2;
    const float* hW[4];   // em es pm ps
    const float* dHW[2];  // dm ds
    uint2* dst;
};

__global__ void prep3(PrepP pp) {
    const int jod[13]  = {128,128,128,384, 128,128,128, 16,16,16,16, 2,2};
    const int jnq[13]  = {40,40,40,40, 32,32,32, 32,32,32,32, 32,32};
    const int jdst[13] = {OF_E1,OF_P1,OF_D1,OF_G, OF_E2,OF_P2,OF_D2,
                          OF_H,OF_H+512,OF_H+1024,OF_H+1536, OF_DH,OF_DH+64};
    const int jkt[3]   = {140,138,154};

    int job = blockIdx.y;
    int od = jod[job], nq = jnq[job];
    int total = A_ * nq * od;
    int idx = blockIdx.x * 256 + threadIdx.x;
    if (idx >= total) return;
    int a = idx / (nq * od);
    int rem = idx - a * (nq * od);
    int q = rem / od;
    int c = rem - q * od;

    float v[4];
#pragma unroll
    for (int i = 0; i < 4; ++i) {
        int k = 4 * q + i;
        float val = 0.f;
        if (job < 3) {
            // unified u index -> source row
            int sk = -1;
            if (job == 0)      sk = (k < 12) ? k : (k >= 32 ? k - 20 : -1);
            else if (job == 1) sk = (k >= 2 && k < 12) ? k - 2 : (k >= 32 ? k - 22 : -1);
            else               sk = (k >= 2 && k < 28) ? k - 2 : (k >= 32 ? k - 6 : -1);
            const float* s = (job == 0) ? pp.eW1 : (job == 1) ? pp.pW1 : pp.dW1;
            if (sk >= 0) val = s[((size_t)a * jkt[job] + sk) * 128 + c];
        } else if (job == 3) {
            // GRU unified: c = gate index 0..383
            if (k < 2)                  val = pp.wih[((size_t)a * 384 + c) * 18 + k];
            else if (k >= 12 && k < 28) val = pp.wih[((size_t)a * 384 + c) * 18 + (k - 10)];
            else if (k >= 32)           val = pp.whh[((size_t)a * 384 + c) * 128 + (k - 32)];
        } else {
            const float* s = (job == 4) ? pp.eW2 : (job == 5) ? pp.pW2 : (job == 6) ? pp.dW2
                           : (job <= 10) ? pp.hW[job - 7] : pp.dHW[job - 11];
            val = s[((size_t)a * 128 + k) * od + c];
        }
        v[i] = val;
    }
    u32 lo = (u32)f2h(v[0]) | ((u32)f2h(v[1]) << 16);
    u32 hi = (u32)f2h(v[2]) | ((u32)f2h(v[3]) << 16);
    pp.dst[(size_t)a * AGU2 + jdst[job] + q * od + c] = make_uint2(lo, hi);
}

__global__ void finish_kernel(const float* __restrict__ partials, float* __restrict__ out) {
    __shared__ float red[256];
    int tid = threadIdx.x;
    red[tid] = (tid < NWG) ? partials[tid] : 0.f;
    __syncthreads();
    for (int s2 = 128; s2 > 0; s2 >>= 1) {
        if (tid < s2) red[tid] += red[tid + s2];
        __syncthreads();
    }
    if (tid == 0) out[0] = red[0];
    __syncthreads();
    red[tid] = (tid < NWG) ? partials[NWG + tid] : 0.f;
    __syncthreads();
    for (int s2 = 128; s2 > 0; s2 >>= 1) {
        if (tid < s2) red[tid] += red[tid + s2];
        __syncthreads();
    }
    if (tid == 0) out[1] = red[0];
}

extern "C" void kernel_launch(void* const* d_in, const int* in_sizes, int n_in,
                              void* d_out, int out_size, void* d_ws, size_t ws_size,
                              hipStream_t stream) {
    float* partials = (float*)d_ws;                 // 320 floats
    uint2* wq = (uint2*)((char*)d_ws + 4096);       // packed weights, ~1.81 MB

    PrepP pp;
    pp.eW1 = (const float*)d_in[2];
    pp.pW1 = (const float*)d_in[10];
    pp.dW1 = (const float*)d_in[18];
    pp.wih = (const float*)d_in[26];
    pp.whh = (const float*)d_in[27];
    pp.eW2 = (const float*)d_in[4];
    pp.pW2 = (const float*)d_in[12];
    pp.dW2 = (const float*)d_in[20];
    pp.hW[0] = (const float*)d_in[6];   // emW
    pp.hW[1] = (const float*)d_in[8];   // esW
    pp.hW[2] = (const float*)d_in[14];  // pmW
    pp.hW[3] = (const float*)d_in[16];  // psW
    pp.dHW[0] = (const float*)d_in[22]; // dmW
    pp.dHW[1] = (const float*)d_in[24]; // dsW
    pp.dst = wq;
    // max job total = 5*40*384 = 76800 -> 300 blocks x 256, y = 13 jobs
    prep3<<<dim3(300, 13), 256, 0, stream>>>(pp);

    P3s p;
    p.y   = (const float*)d_in[0];
    p.eps = (const float*)d_in[1];
    p.eb1 = (const float*)d_in[3];  p.eb2 = (const float*)d_in[5];
    p.emb = (const float*)d_in[7];  p.esb = (const float*)d_in[9];
    p.pb1 = (const float*)d_in[11]; p.pb2 = (const float*)d_in[13];
    p.pmb = (const float*)d_in[15]; p.psb = (const float*)d_in[17];
    p.db1 = (const float*)d_in[19]; p.db2 = (const float*)d_in[21];
    p.dmb = (const float*)d_in[23]; p.dsb = (const float*)d_in[25];
    p.bih = (const float*)d_in[28]; p.bhh = (const float*)d_in[29];
    p.wq = wq;
    p.partials = partials;

    vrnn3<<<NWG, NTH, 0, stream>>>(p);
    finish_kernel<<<1, 256, 0, stream>>>(partials, (float*)d_out);
}

// Round 4
// 1031.539 us; speedup vs baseline: 4.3742x; 1.0593x over previous
//
#include <hip/hip_runtime.h>
#include <math.h>

typedef unsigned int u32;
typedef unsigned short u16;

#define NS 128          // T-1 timesteps
#define A_ 5
#define B_ 128
#define NTH 512
#define NWG 160         // 5 agents x 32 chunks of 4 rows
#define LOG2PI_F 1.8378770664093453f

// ---- packed weight layout (uint2 = 4 f16 units), per agent ----
// U-layers use the unified 160-elem input [x2 y10 z16 pad4 h128] = 40 quads,
// with zero weights where a layer doesn't consume a slot.
#define OF_E1 0         // 40q x 128
#define OF_P1 5120
#define OF_D1 10240
#define OF_G  15360     // 40q x 384 (3 gates x 128)
#define OF_E2 30720     // 32q x 128
#define OF_P2 34816
#define OF_D2 38912
#define OF_H  43008     // 4 heads x (32q x 16)
#define OF_DH 45056     // 2 heads x (32q x 2)
#define AGU2  45184

typedef _Float16 half2v __attribute__((ext_vector_type(2)));

__device__ __forceinline__ float fdot2(u32 w, u32 x, float acc) {
#if __has_builtin(__builtin_amdgcn_fdot2)
    return __builtin_amdgcn_fdot2(__builtin_bit_cast(half2v, w),
                                  __builtin_bit_cast(half2v, x), acc, false);
#else
    half2v a = __builtin_bit_cast(half2v, w), b = __builtin_bit_cast(half2v, x);
    return acc + (float)a.x * (float)b.x + (float)a.y * (float)b.y;
#endif
}
__device__ __forceinline__ u16 f2h(float f) { _Float16 h = (_Float16)f; return __builtin_bit_cast(u16, h); }
__device__ __forceinline__ float h2f(u16 u) { return (float)__builtin_bit_cast(_Float16, u); }
__device__ __forceinline__ float softplusf_(float x) { return fmaxf(x, 0.f) + log1pf(expf(-fabsf(x))); }
__device__ __forceinline__ float sigmoidf_(float x) { return 1.f / (1.f + expf(-x)); }

#define RED16_32(v) { v += __shfl_xor(v, 16); v += __shfl_xor(v, 32); }
#define SEL4(k, v0, v1, v2, v3) ((k)==0 ? (v0) : (k)==1 ? (v1) : (k)==2 ? (v2) : (v3))
// Pin a value into a VGPR: opaque to the optimizer, so loop-invariant loads
// cannot be sunk back into the t-loop (R3 failure: VGPR_Count=128 proved sinking).
#define PINU2(w) asm volatile("" : "+v"((w).x), "+v"((w).y))
#define PINF(f)  asm volatile("" : "+v"(f))

struct P3s {
    const float* __restrict__ y;
    const float* __restrict__ eps;
    const float* __restrict__ eb1; const float* __restrict__ eb2;
    const float* __restrict__ pb1; const float* __restrict__ pb2;
    const float* __restrict__ db1; const float* __restrict__ db2;
    const float* __restrict__ emb; const float* __restrict__ esb;
    const float* __restrict__ pmb; const float* __restrict__ psb;
    const float* __restrict__ dmb; const float* __restrict__ dsb;
    const float* __restrict__ bih; const float* __restrict__ bhh;
    const uint2* __restrict__ wq;
    float* __restrict__ partials;
};

__global__ void __launch_bounds__(NTH, 2) vrnn4(P3s p) {
    const int tid = threadIdx.x;
    const int a = blockIdx.x >> 5;
    const int b0 = (blockIdx.x & 31) * 4;
    const int wave = tid >> 6;
    const int lane = tid & 63;
    const int o = wave * 16 + (lane & 15);   // output column 0..127
    const int k4 = lane >> 4;                // K-quarter / row id 0..3
    const bool k0 = (k4 == 0);

    __shared__ __align__(16) u16 U[4][160];          // [x2 y10 z16 pad4 h128]
    __shared__ __align__(16) u16 aA[4][128], aB[4][128], aC[4][128], aD[4][128];
    __shared__ float mue[4][16], sde[4][16], mup[4][16], sdp[4][16];
    __shared__ float xf[4][2], dmu[4][2], dsd[4][2];
    __shared__ uint2 whLDS[2048];   // 4 heads x 32q x 16
    __shared__ uint2 wdhLDS[128];   // 2 heads x 32q x 2
    __shared__ float red[NTH];

    const uint2* WA = p.wq + (size_t)a * AGU2;

    // ---- init LDS: zero U (pad + h), copy head weights ----
    for (int i = tid; i < 4 * 160; i += NTH) (&U[0][0])[i] = 0;
    for (int i = tid; i < 2048; i += NTH) whLDS[i] = WA[OF_H + i];
    if (tid < 128) wdhLDS[tid] = WA[OF_DH + tid];

    // ---- register-resident weights (loop-invariant, PINNED) ----
    uint2 wE1[10], wP1[10], wD1[10], wG0[10], wG1[10], wG2[10];
    uint2 wE2[8], wP2[8], wD2[8];
#pragma unroll
    for (int j = 0; j < 10; ++j) {
        int q = k4 * 10 + j;
        wE1[j] = WA[OF_E1 + q * 128 + o];
        wP1[j] = WA[OF_P1 + q * 128 + o];
        wD1[j] = WA[OF_D1 + q * 128 + o];
        wG0[j] = WA[OF_G + q * 384 + o];
        wG1[j] = WA[OF_G + q * 384 + 128 + o];
        wG2[j] = WA[OF_G + q * 384 + 256 + o];
    }
#pragma unroll
    for (int j = 0; j < 8; ++j) {
        int q = k4 * 8 + j;
        wE2[j] = WA[OF_E2 + q * 128 + o];
        wP2[j] = WA[OF_P2 + q * 128 + o];
        wD2[j] = WA[OF_D2 + q * 128 + o];
    }
#pragma unroll
    for (int j = 0; j < 10; ++j) {
        PINU2(wE1[j]); PINU2(wP1[j]); PINU2(wD1[j]);
        PINU2(wG0[j]); PINU2(wG1[j]); PINU2(wG2[j]);
    }
#pragma unroll
    for (int j = 0; j < 8; ++j) { PINU2(wE2[j]); PINU2(wP2[j]); PINU2(wD2[j]); }

    // ---- register-resident biases (pinned) ----
    float rbE1 = p.eb1[a * 128 + o], rbE2 = p.eb2[a * 128 + o];
    float rbP1 = p.pb1[a * 128 + o], rbP2 = p.pb2[a * 128 + o];
    float rbD1 = p.db1[a * 128 + o], rbD2 = p.db2[a * 128 + o];
    float rbI0 = p.bih[a * 384 + o], rbI1 = p.bih[a * 384 + 128 + o], rbI2 = p.bih[a * 384 + 256 + o];
    float rbH0 = p.bhh[a * 384 + o], rbH1 = p.bhh[a * 384 + 128 + o], rbH2 = p.bhh[a * 384 + 256 + o];
    const int headH = wave & 3, zdH = lane & 15, rH = (wave >> 2) * 2;
    float rbH = ((headH == 0) ? p.emb : (headH == 1) ? p.esb
               : (headH == 2) ? p.pmb : p.psb)[a * 16 + zdH];
    const int outD = tid >> 5, partD = tid & 31;
    const int headD = outD >> 3, subD = outD & 7, rD = subD >> 1, xdD = subD & 1;
    float rbDH = (headD ? p.dsb : p.dmb)[a * 2 + xdD];
    PINF(rbE1); PINF(rbE2); PINF(rbP1); PINF(rbP2); PINF(rbD1); PINF(rbD2);
    PINF(rbI0); PINF(rbI1); PINF(rbI2); PINF(rbH0); PINF(rbH1); PINF(rbH2);
    PINF(rbH); PINF(rbDH);

    // ---- per-row LDS base pointers (k4-offset folded in) ----
    const u16* Ub[4];  const u16* aAb[4]; const u16* aBb[4]; const u16* aCb[4]; const u16* aDb[4];
#pragma unroll
    for (int r = 0; r < 4; ++r) {
        Ub[r]  = &U[r][0]  + k4 * 40;   // 10 quads * 4 u16
        aAb[r] = &aA[r][0] + k4 * 32;   // 8 quads * 4 u16
        aBb[r] = &aB[r][0] + k4 * 32;
        aCb[r] = &aC[r][0] + k4 * 32;
        aDb[r] = &aD[r][0] + k4 * 32;
    }

    // ---- prefetch t=0 inputs into registers ----
    const int ry = tid / 10, jy = tid - ry * 10;            // tid<40
    const int rx = (tid - 40) >> 1, xdx = (tid - 40) & 1;   // 40<=tid<48
    const int re = tid >> 4, ze = tid & 15;                 // tid<64
    float ypre = 0.f, xpre = 0.f, epre = 0.f;
    if (tid < 40) ypre = p.y[0 * (B_ * 10) + (b0 + ry) * 10 + jy];
    else if (tid < 48) xpre = p.y[1 * (B_ * 10) + (b0 + rx) * 10 + a * 2 + xdx];
    if (tid < 64) epre = p.eps[(((size_t)0 * A_ + a) * B_ + (b0 + re)) * 16 + ze];

    float kl_acc = 0.f, nll_acc = 0.f, hnew = 0.f;

#pragma unroll 1
    for (int t = 0; t < NS; ++t) {
        const int tn = (t + 1 < NS) ? t + 1 : t;
        __syncthreads();
        // ---- P1: commit prefetched inputs, issue next prefetch ----
        if (tid < 40) {
            U[ry][2 + jy] = f2h(ypre);
            ypre = p.y[tn * (B_ * 10) + (b0 + ry) * 10 + jy];
        } else if (tid < 48) {
            U[rx][xdx] = f2h(xpre); xf[rx][xdx] = xpre;
            xpre = p.y[(tn + 1) * (B_ * 10) + (b0 + rx) * 10 + a * 2 + xdx];
        }
        __syncthreads();

        // ---- P2: enc1 + pri1 (shared U reads) ----
        {
            float aE[4], aP[4];
#pragma unroll
            for (int r = 0; r < 4; ++r) { aE[r] = k0 ? rbE1 : 0.f; aP[r] = k0 ? rbP1 : 0.f; }
#pragma unroll
            for (int pp = 0; pp < 5; ++pp) {
#pragma unroll
                for (int r = 0; r < 4; ++r) {
                    uint4 xv = *(const uint4*)(Ub[r] + pp * 8);
                    aE[r] = fdot2(wE1[2*pp].x,   xv.x, aE[r]);
                    aE[r] = fdot2(wE1[2*pp].y,   xv.y, aE[r]);
                    aE[r] = fdot2(wE1[2*pp+1].x, xv.z, aE[r]);
                    aE[r] = fdot2(wE1[2*pp+1].y, xv.w, aE[r]);
                    aP[r] = fdot2(wP1[2*pp].x,   xv.x, aP[r]);
                    aP[r] = fdot2(wP1[2*pp].y,   xv.y, aP[r]);
                    aP[r] = fdot2(wP1[2*pp+1].x, xv.z, aP[r]);
                    aP[r] = fdot2(wP1[2*pp+1].y, xv.w, aP[r]);
                }
            }
#pragma unroll
            for (int r = 0; r < 4; ++r) { RED16_32(aE[r]); RED16_32(aP[r]); }
            float vE = SEL4(k4, aE[0], aE[1], aE[2], aE[3]);
            float vP = SEL4(k4, aP[0], aP[1], aP[2], aP[3]);
            aA[k4][o] = f2h(fmaxf(vE, 0.f));
            aC[k4][o] = f2h(fmaxf(vP, 0.f));
        }
        __syncthreads();

        // ---- P3: enc2 (aA->aB), pri2 (aC->aD) ----
        {
            float aE[4], aP[4];
#pragma unroll
            for (int r = 0; r < 4; ++r) { aE[r] = k0 ? rbE2 : 0.f; aP[r] = k0 ? rbP2 : 0.f; }
#pragma unroll
            for (int pp = 0; pp < 4; ++pp) {
#pragma unroll
                for (int r = 0; r < 4; ++r) {
                    uint4 xa = *(const uint4*)(aAb[r] + pp * 8);
                    uint4 xc = *(const uint4*)(aCb[r] + pp * 8);
                    aE[r] = fdot2(wE2[2*pp].x,   xa.x, aE[r]);
                    aE[r] = fdot2(wE2[2*pp].y,   xa.y, aE[r]);
                    aE[r] = fdot2(wE2[2*pp+1].x, xa.z, aE[r]);
                    aE[r] = fdot2(wE2[2*pp+1].y, xa.w, aE[r]);
                    aP[r] = fdot2(wP2[2*pp].x,   xc.x, aP[r]);
                    aP[r] = fdot2(wP2[2*pp].y,   xc.y, aP[r]);
                    aP[r] = fdot2(wP2[2*pp+1].x, xc.z, aP[r]);
                    aP[r] = fdot2(wP2[2*pp+1].y, xc.w, aP[r]);
                }
            }
#pragma unroll
            for (int r = 0; r < 4; ++r) { RED16_32(aE[r]); RED16_32(aP[r]); }
            float vE = SEL4(k4, aE[0], aE[1], aE[2], aE[3]);
            float vP = SEL4(k4, aP[0], aP[1], aP[2], aP[3]);
            aB[k4][o] = f2h(fmaxf(vE, 0.f));
            aD[k4][o] = f2h(fmaxf(vP, 0.f));
        }
        __syncthreads();

        // ---- P4: 4 gaussian heads (128->16), weights from LDS ----
        {
            const u16* s0p = (headH < 2) ? &aB[rH][0]     : &aD[rH][0];
            const u16* s1p = (headH < 2) ? &aB[rH + 1][0] : &aD[rH + 1][0];
            float e0 = k0 ? rbH : 0.f, e1 = k0 ? rbH : 0.f;
#pragma unroll
            for (int pp = 0; pp < 4; ++pp) {
                int q = k4 * 8 + 2 * pp;
                uint2 w0 = whLDS[headH * 512 + q * 16 + zdH];
                uint2 w1 = whLDS[headH * 512 + (q + 1) * 16 + zdH];
                uint4 x0 = *(const uint4*)(s0p + k4 * 32 + pp * 8);
                uint4 x1 = *(const uint4*)(s1p + k4 * 32 + pp * 8);
                e0 = fdot2(w0.x, x0.x, e0); e0 = fdot2(w0.y, x0.y, e0);
                e0 = fdot2(w1.x, x0.z, e0); e0 = fdot2(w1.y, x0.w, e0);
                e1 = fdot2(w0.x, x1.x, e1); e1 = fdot2(w0.y, x1.y, e1);
                e1 = fdot2(w1.x, x1.z, e1); e1 = fdot2(w1.y, x1.w, e1);
            }
            RED16_32(e0); RED16_32(e1);
            if (k4 < 2) {
                float v = (k4 == 0) ? e0 : e1;
                int r = rH + k4;
                if (headH == 0)      mue[r][zdH] = v;
                else if (headH == 1) sde[r][zdH] = softplusf_(v);
                else if (headH == 2) mup[r][zdH] = v;
                else                 sdp[r][zdH] = softplusf_(v);
            }
        }
        __syncthreads();

        // ---- P5: z sample + KL (eps was prefetched) ----
        if (tid < 64) {
            float em = mue[re][ze], es = sde[re][ze], pm = mup[re][ze], ps = sdp[re][ze];
            float zv = fmaf(epre, es, em);
            U[re][12 + ze] = f2h(zv);
            float dm = em - pm;
            kl_acc += 0.5f * (2.f * (logf(ps) - logf(es)) + (es * es + dm * dm) / (ps * ps) - 1.f);
            epre = p.eps[(((size_t)tn * A_ + a) * B_ + (b0 + re)) * 16 + ze];
        }
        __syncthreads();

        // ---- P6: dec1 + GRU (shared U reads) ----
        {
            float aO[4], s0[4], s1[4], g2a[4], g2b[4];
#pragma unroll
            for (int r = 0; r < 4; ++r) {
                aO[r]  = k0 ? rbD1 : 0.f;
                s0[r]  = k0 ? (rbI0 + rbH0) : 0.f;
                s1[r]  = k0 ? (rbI1 + rbH1) : 0.f;
                g2a[r] = k0 ? rbI2 : 0.f;
                g2b[r] = k0 ? rbH2 : 0.f;
            }
#pragma unroll
            for (int pp = 0; pp < 5; ++pp) {
#pragma unroll
                for (int r = 0; r < 4; ++r) {
                    uint4 xv = *(const uint4*)(Ub[r] + pp * 8);
                    aO[r] = fdot2(wD1[2*pp].x,   xv.x, aO[r]);
                    aO[r] = fdot2(wD1[2*pp].y,   xv.y, aO[r]);
                    aO[r] = fdot2(wD1[2*pp+1].x, xv.z, aO[r]);
                    aO[r] = fdot2(wD1[2*pp+1].y, xv.w, aO[r]);
                    s0[r] = fdot2(wG0[2*pp].x,   xv.x, s0[r]);
                    s0[r] = fdot2(wG0[2*pp].y,   xv.y, s0[r]);
                    s0[r] = fdot2(wG0[2*pp+1].x, xv.z, s0[r]);
                    s0[r] = fdot2(wG0[2*pp+1].y, xv.w, s0[r]);
                    s1[r] = fdot2(wG1[2*pp].x,   xv.x, s1[r]);
                    s1[r] = fdot2(wG1[2*pp].y,   xv.y, s1[r]);
                    s1[r] = fdot2(wG1[2*pp+1].x, xv.z, s1[r]);
                    s1[r] = fdot2(wG1[2*pp+1].y, xv.w, s1[r]);
                    // gate-2: pairs 0-3 cover u<32 (ih region for k4==0), pair 4 covers h
                    float& g2 = (pp < 4) ? g2a[r] : g2b[r];
                    g2 = fdot2(wG2[2*pp].x,   xv.x, g2);
                    g2 = fdot2(wG2[2*pp].y,   xv.y, g2);
                    g2 = fdot2(wG2[2*pp+1].x, xv.z, g2);
                    g2 = fdot2(wG2[2*pp+1].y, xv.w, g2);
                }
            }
            float gi2[4], gh2[4];
#pragma unroll
            for (int r = 0; r < 4; ++r) {
                gi2[r] = k0 ? g2a[r] : 0.f;
                gh2[r] = k0 ? g2b[r] : (g2a[r] + g2b[r]);
            }
#pragma unroll
            for (int r = 0; r < 4; ++r) {
                RED16_32(aO[r]); RED16_32(s0[r]); RED16_32(s1[r]);
                RED16_32(gi2[r]); RED16_32(gh2[r]);
            }
            float vD = SEL4(k4, aO[0], aO[1], aO[2], aO[3]);
            float rs = SEL4(k4, s0[0], s0[1], s0[2], s0[3]);
            float zs = SEL4(k4, s1[0], s1[1], s1[2], s1[3]);
            float i2 = SEL4(k4, gi2[0], gi2[1], gi2[2], gi2[3]);
            float hh2 = SEL4(k4, gh2[0], gh2[1], gh2[2], gh2[3]);
            float rr = sigmoidf_(rs);
            float zz = sigmoidf_(zs);
            float nn = tanhf(fmaf(rr, hh2, i2));
            float hold = h2f(U[k4][32 + o]);
            hnew = fmaf(zz, hold - nn, nn);
            aA[k4][o] = f2h(fmaxf(vD, 0.f));
        }
        __syncthreads();

        // ---- P7: dec2 (aA -> aB) ----
        {
            float aE[4];
#pragma unroll
            for (int r = 0; r < 4; ++r) aE[r] = k0 ? rbD2 : 0.f;
#pragma unroll
            for (int pp = 0; pp < 4; ++pp) {
#pragma unroll
                for (int r = 0; r < 4; ++r) {
                    uint4 xa = *(const uint4*)(aAb[r] + pp * 8);
                    aE[r] = fdot2(wD2[2*pp].x,   xa.x, aE[r]);
                    aE[r] = fdot2(wD2[2*pp].y,   xa.y, aE[r]);
                    aE[r] = fdot2(wD2[2*pp+1].x, xa.z, aE[r]);
                    aE[r] = fdot2(wD2[2*pp+1].y, xa.w, aE[r]);
                }
            }
#pragma unroll
            for (int r = 0; r < 4; ++r) RED16_32(aE[r]);
            float vE = SEL4(k4, aE[0], aE[1], aE[2], aE[3]);
            aB[k4][o] = f2h(fmaxf(vE, 0.f));
        }
        __syncthreads();

        // ---- P8: h write + dec heads (128->2) ----
        U[k4][32 + o] = f2h(hnew);
        {
            uint2 w = wdhLDS[headD * 64 + partD * 2 + xdD];
            uint2 xa = *(const uint2*)(&aB[rD][0] + partD * 4);
            float s = fdot2(w.x, xa.x, 0.f);
            s = fdot2(w.y, xa.y, s);
            s += __shfl_xor(s, 1); s += __shfl_xor(s, 2); s += __shfl_xor(s, 4);
            s += __shfl_xor(s, 8); s += __shfl_xor(s, 16);
            if (partD == 0) {
                float v = rbDH + s;
                if (headD) dsd[rD][xdD] = softplusf_(v);
                else       dmu[rD][xdD] = v;
            }
        }
        __syncthreads();

        // ---- P9: NLL ----
        if (tid < 8) {
            int r = tid >> 1, xd = tid & 1;
            float d = xf[r][xd] - dmu[r][xd];
            float sd = dsd[r][xd];
            nll_acc += 0.5f * (d * d / (sd * sd) + 2.f * logf(sd) + LOG2PI_F);
        }
    }

    // ---- block reductions ----
    __syncthreads();
    red[tid] = kl_acc; __syncthreads();
    for (int s2 = NTH / 2; s2 > 0; s2 >>= 1) {
        if (tid < s2) red[tid] += red[tid + s2];
        __syncthreads();
    }
    if (tid == 0) p.partials[blockIdx.x] = red[0];
    __syncthreads();
    red[tid] = nll_acc; __syncthreads();
    for (int s2 = NTH / 2; s2 > 0; s2 >>= 1) {
        if (tid < s2) red[tid] += red[tid + s2];
        __syncthreads();
    }
    if (tid == 0) p.partials[NWG + blockIdx.x] = red[0];
}

// ---------------- prep: pack weights into unified zero-padded f16 quads ----------------
struct PrepP {
    const float* eW1; const float* pW1; const float* dW1;
    const float* wih; const float* whh;
    const float* eW2; const float* pW2; const float* dW2;
    const float* hW[4];   // em es pm ps
    const float* dHW[2];  // dm ds
    uint2* dst;
};

__global__ void prep3(PrepP pp) {
    const int jod[13]  = {128,128,128,384, 128,128,128, 16,16,16,16, 2,2};
    const int jnq[13]  = {40,40,40,40, 32,32,32, 32,32,32,32, 32,32};
    const int jdst[13] = {OF_E1,OF_P1,OF_D1,OF_G, OF_E2,OF_P2,OF_D2,
                          OF_H,OF_H+512,OF_H+1024,OF_H+1536, OF_DH,OF_DH+64};
    const int jkt[3]   = {140,138,154};

    int job = blockIdx.y;
    int od = jod[job], nq = jnq[job];
    int total = A_ * nq * od;
    int idx = blockIdx.x * 256 + threadIdx.x;
    if (idx >= total) return;
    int a = idx / (nq * od);
    int rem = idx - a * (nq * od);
    int q = rem / od;
    int c = rem - q * od;

    float v[4];
#pragma unroll
    for (int i = 0; i < 4; ++i) {
        int k = 4 * q + i;
        float val = 0.f;
        if (job < 3) {
            // unified u index -> source row
            int sk = -1;
            if (job == 0)      sk = (k < 12) ? k : (k >= 32 ? k - 20 : -1);
            else if (job == 1) sk = (k >= 2 && k < 12) ? k - 2 : (k >= 32 ? k - 22 : -1);
            else               sk = (k >= 2 && k < 28) ? k - 2 : (k >= 32 ? k - 6 : -1);
            const float* s = (job == 0) ? pp.eW1 : (job == 1) ? pp.pW1 : pp.dW1;
            if (sk >= 0) val = s[((size_t)a * jkt[job] + sk) * 128 + c];
        } else if (job == 3) {
            // GRU unified: c = gate index 0..383
            if (k < 2)                  val = pp.wih[((size_t)a * 384 + c) * 18 + k];
            else if (k >= 12 && k < 28) val = pp.wih[((size_t)a * 384 + c) * 18 + (k - 10)];
            else if (k >= 32)           val = pp.whh[((size_t)a * 384 + c) * 128 + (k - 32)];
        } else {
            const float* s = (job == 4) ? pp.eW2 : (job == 5) ? pp.pW2 : (job == 6) ? pp.dW2
                           : (job <= 10) ? pp.hW[job - 7] : pp.dHW[job - 11];
            val = s[((size_t)a * 128 + k) * od + c];
        }
        v[i] = val;
    }
    u32 lo = (u32)f2h(v[0]) | ((u32)f2h(v[1]) << 16);
    u32 hi = (u32)f2h(v[2]) | ((u32)f2h(v[3]) << 16);
    pp.dst[(size_t)a * AGU2 + jdst[job] + q * od + c] = make_uint2(lo, hi);
}

__global__ void finish_kernel(const float* __restrict__ partials, float* __restrict__ out) {
    __shared__ float red[256];
    int tid = threadIdx.x;
    red[tid] = (tid < NWG) ? partials[tid] : 0.f;
    __syncthreads();
    for (int s2 = 128; s2 > 0; s2 >>= 1) {
        if (tid < s2) red[tid] += red[tid + s2];
        __syncthreads();
    }
    if (tid == 0) out[0] = red[0];
    __syncthreads();
    red[tid] = (tid < NWG) ? partials[NWG + tid] : 0.f;
    __syncthreads();
    for (int s2 = 128; s2 > 0; s2 >>= 1) {
        if (tid < s2) red[tid] += red[tid + s2];
        __syncthreads();
    }
    if (tid == 0) out[1] = red[0];
}

extern "C" void kernel_launch(void* const* d_in, const int* in_sizes, int n_in,
                              void* d_out, int out_size, void* d_ws, size_t ws_size,
                              hipStream_t stream) {
    float* partials = (float*)d_ws;                 // 320 floats
    uint2* wq = (uint2*)((char*)d_ws + 4096);       // packed weights, ~1.81 MB

    PrepP pp;
    pp.eW1 = (const float*)d_in[2];
    pp.pW1 = (const float*)d_in[10];
    pp.dW1 = (const float*)d_in[18];
    pp.wih = (const float*)d_in[26];
    pp.whh = (const float*)d_in[27];
    pp.eW2 = (const float*)d_in[4];
    pp.pW2 = (const float*)d_in[12];
    pp.dW2 = (const float*)d_in[20];
    pp.hW[0] = (const float*)d_in[6];   // emW
    pp.hW[1] = (const float*)d_in[8];   // esW
    pp.hW[2] = (const float*)d_in[14];  // pmW
    pp.hW[3] = (const float*)d_in[16];  // psW
    pp.dHW[0] = (const float*)d_in[22]; // dmW
    pp.dHW[1] = (const float*)d_in[24]; // dsW
    pp.dst = wq;
    // max job total = 5*40*384 = 76800 -> 300 blocks x 256, y = 13 jobs
    prep3<<<dim3(300, 13), 256, 0, stream>>>(pp);

    P3s p;
    p.y   = (const float*)d_in[0];
    p.eps = (const float*)d_in[1];
    p.eb1 = (const float*)d_in[3];  p.eb2 = (const float*)d_in[5];
    p.emb = (const float*)d_in[7];  p.esb = (const float*)d_in[9];
    p.pb1 = (const float*)d_in[11]; p.pb2 = (const float*)d_in[13];
    p.pmb = (const float*)d_in[15]; p.psb = (const float*)d_in[17];
    p.db1 = (const float*)d_in[19]; p.db2 = (const float*)d_in[21];
    p.dmb = (const float*)d_in[23]; p.dsb = (const float*)d_in[25];
    p.bih = (const float*)d_in[28]; p.bhh = (const float*)d_in[29];
    p.wq = wq;
    p.partials = partials;

    vrnn4<<<NWG, NTH, 0, stream>>>(p);
    finish_kernel<<<1, 256, 0, stream>>>(partials, (float*)d_out);
}